// Round 3
// baseline (922.694 us; speedup 1.0000x reference)
//
#include <hip/hip_runtime.h>

typedef unsigned short u16;
typedef unsigned int u32;
typedef __attribute__((ext_vector_type(4))) float f32x4;
typedef __attribute__((ext_vector_type(8))) short s16x8;

#define GM 262144   // B*N rows
#define GB 64
#define GN 4096
#define GC 256
#define GD 256
#define GS 8
#define GH 512
#define CH 16       // attn chunks per batch

__device__ __forceinline__ float bf2f(u16 u) {
  union { unsigned int i; float f; } c; c.i = ((unsigned int)u) << 16; return c.f;
}
__device__ __forceinline__ u16 f2bf(float f) {
  union { float f; unsigned int i; } c; c.f = f;
  unsigned int x = c.i;
  unsigned int r = x + 0x7FFFu + ((x >> 16) & 1u);
  return (u16)(r >> 16);
}
__device__ __forceinline__ float dot4(f32x4 a, f32x4 b) {
  return a.x*b.x + a.y*b.y + a.z*b.z + a.w*b.w;
}

// ---------------- slots init: mu + exp(log_sigma)*noise ----------------
__global__ void init_slots_kernel(const float* __restrict__ noise, const float* __restrict__ smu,
                                  const float* __restrict__ sls, float* __restrict__ slots)
{
  int i = blockIdx.x * 256 + threadIdx.x;   // 131072 total
  int d = i & 255;
  slots[i] = smu[d] + expf(sls[d]) * noise[i];
}

// ---------------- weight convert fp32->bf16 (Wk rows 0..255, Wv rows 256..511) ----------------
__global__ void wconv_kernel(const float* __restrict__ Wk, const float* __restrict__ Wv, u16* __restrict__ wkv)
{
  int i = blockIdx.x * 256 + threadIdx.x;   // 65536
  wkv[i] = f2bf(Wk[i]);
  wkv[i + 65536] = f2bf(Wv[i]);
}

// ---------------- fused LN-stats + LN + K/V projection (bf16 MFMA, barrier-free k-loop) ----------
// block: 512 thr (8 waves). tile: 64 rows x 512 out-cols (K cols 0..255 -> kbuf row-major,
// V cols -> vtbuf transposed tiles). Waves 0-3: K (64x64 each), waves 4-7: V.
__global__ __launch_bounds__(512) void gemm_kv(
    const float* __restrict__ x, const u16* __restrict__ wkv,
    const float* __restrict__ lng, const float* __restrict__ lnb,
    u16* __restrict__ kbuf, u16* __restrict__ vtbuf)
{
  __shared__ __align__(16) u16 lnx[64 * 264];
  __shared__ float2 mur[64];
  const int t = threadIdx.x;
  const int brow = blockIdx.x * 64;
  const int lane = t & 63, w = t >> 6;
  const int fr = lane & 15, fq = lane >> 4;

  // ---- pass 1: load x tile (coalesced, once from HBM), stats per row, store bf16 pre-LN ----
  {
    float s[8], sq[8];
    const int c4 = lane;           // wait: need 64 col-groups -> use t&63
    #pragma unroll
    for (int seg = 0; seg < 8; ++seg) {
      int row = w + seg * 8;
      f32x4 v = *(const f32x4*)&x[(size_t)(brow + row) * 256 + (t & 63) * 4];
      uint2 pk;
      pk.x = (u32)f2bf(v.x) | ((u32)f2bf(v.y) << 16);
      pk.y = (u32)f2bf(v.z) | ((u32)f2bf(v.w) << 16);
      *(uint2*)&lnx[row * 264 + (t & 63) * 4] = pk;
      s[seg] = v.x + v.y + v.z + v.w;
      sq[seg] = v.x*v.x + v.y*v.y + v.z*v.z + v.w*v.w;
    }
    (void)c4;
    #pragma unroll
    for (int seg = 0; seg < 8; ++seg) {
      #pragma unroll
      for (int m = 1; m < 64; m <<= 1) {
        s[seg] += __shfl_xor(s[seg], m, 64);
        sq[seg] += __shfl_xor(sq[seg], m, 64);
      }
      if (lane == 0) {
        int row = w + seg * 8;
        float mu = s[seg] * (1.f / 256.f);
        float var = sq[seg] * (1.f / 256.f) - mu * mu;
        mur[row] = make_float2(mu, rsqrtf(var + 1e-3f));
      }
    }
  }
  __syncthreads();

  // ---- pass 2: in-place LN transform (32 elems/thread) ----
  {
    int row = t >> 3, c0 = (t & 7) * 32;
    float2 mr = mur[row];
    #pragma unroll
    for (int c = 0; c < 32; c += 4) {
      uint2 pk = *(uint2*)&lnx[row * 264 + c0 + c];
      float v0 = bf2f((u16)(pk.x & 0xffff)), v1 = bf2f((u16)(pk.x >> 16));
      float v2 = bf2f((u16)(pk.y & 0xffff)), v3 = bf2f((u16)(pk.y >> 16));
      f32x4 gv = *(const f32x4*)&lng[c0 + c];
      f32x4 bv = *(const f32x4*)&lnb[c0 + c];
      pk.x = (u32)f2bf((v0 - mr.x) * mr.y * gv.x + bv.x)
           | ((u32)f2bf((v1 - mr.x) * mr.y * gv.y + bv.y) << 16);
      pk.y = (u32)f2bf((v2 - mr.x) * mr.y * gv.z + bv.z)
           | ((u32)f2bf((v3 - mr.x) * mr.y * gv.w + bv.w) << 16);
      *(uint2*)&lnx[row * 264 + c0 + c] = pk;
    }
  }
  __syncthreads();

  // ---- barrier-free k-loop: A-frags from LDS, B-frags from L2-hot global weights ----
  const int g = w >> 2, wcol = (w & 3) * 64;
  const u16* wg = &wkv[(size_t)(g * 256 + wcol) * 256];
  f32x4 acc[4][4];
  #pragma unroll
  for (int i = 0; i < 4; ++i)
    #pragma unroll
    for (int j = 0; j < 4; ++j) { f32x4 z = {0.f,0.f,0.f,0.f}; acc[i][j] = z; }

  #pragma unroll
  for (int kk = 0; kk < 256; kk += 32) {
    s16x8 af[4], bf[4];
    #pragma unroll
    for (int i = 0; i < 4; ++i) af[i] = *(const s16x8*)&lnx[(i * 16 + fr) * 264 + kk + fq * 8];
    #pragma unroll
    for (int j = 0; j < 4; ++j) bf[j] = *(const s16x8*)&wg[(size_t)(j * 16 + fr) * 256 + kk + fq * 8];
    #pragma unroll
    for (int i = 0; i < 4; ++i)
      #pragma unroll
      for (int j = 0; j < 4; ++j)
        acc[i][j] = __builtin_amdgcn_mfma_f32_16x16x32_bf16(af[i], bf[j], acc[i][j], 0, 0, 0);
  }

  // ---- epilogue ----
  if (g == 0) {
    #pragma unroll
    for (int i = 0; i < 4; ++i)
      #pragma unroll
      for (int j = 0; j < 4; ++j)
        #pragma unroll
        for (int r = 0; r < 4; ++r)
          kbuf[(size_t)(brow + i * 16 + fq * 4 + r) * 256 + wcol + j * 16 + fr] = f2bf(acc[i][j][r]);
  } else {
    size_t base = (size_t)(brow >> 6) * 16384;   // (b*64 + nc) * 256 * 64
    #pragma unroll
    for (int i = 0; i < 4; ++i)
      #pragma unroll
      for (int j = 0; j < 4; ++j)
        #pragma unroll
        for (int r = 0; r < 4; ++r)
          vtbuf[base + (size_t)(wcol + j * 16 + fr) * 64 + (i * 16 + fq * 4 + r)] = f2bf(acc[i][j][r]);
  }
}

// ---------------- slot LN + q projection, all 8 slots per batch in one block ----------------
__global__ __launch_bounds__(256) void qproj_kernel(const float* __restrict__ slots, const float* __restrict__ Wq,
    const float* __restrict__ g, const float* __restrict__ be, float* __restrict__ gq)
{
  __shared__ __align__(16) float sl[8][256];
  int b = blockIdx.x, t = threadIdx.x;
  int lane = t & 63, w = t >> 6;
  #pragma unroll
  for (int s2 = 0; s2 < 2; ++s2) {
    int s = w * 2 + s2;
    f32x4 v = *(const f32x4*)&slots[(size_t)(b * 8 + s) * 256 + lane * 4];
    float s1 = v.x + v.y + v.z + v.w;
    float q1 = v.x*v.x + v.y*v.y + v.z*v.z + v.w*v.w;
    #pragma unroll
    for (int m = 1; m < 64; m <<= 1) { s1 += __shfl_xor(s1, m, 64); q1 += __shfl_xor(q1, m, 64); }
    float mu = s1 * (1.f / 256.f);
    float var = q1 * (1.f / 256.f) - mu * mu;
    float rstd = rsqrtf(var + 1e-3f);
    f32x4 gv = *(const f32x4*)&g[lane * 4];
    f32x4 bv = *(const f32x4*)&be[lane * 4];
    f32x4 o;
    o.x = (v.x - mu) * rstd * gv.x + bv.x;
    o.y = (v.y - mu) * rstd * gv.y + bv.y;
    o.z = (v.z - mu) * rstd * gv.z + bv.z;
    o.w = (v.w - mu) * rstd * gv.w + bv.w;
    *(f32x4*)&sl[s][lane * 4] = o;
  }
  __syncthreads();
  float a[8];
  #pragma unroll
  for (int s = 0; s < 8; ++s) a[s] = 0.f;
  const f32x4* wr = (const f32x4*)&Wq[(size_t)t * 256];
  for (int k = 0; k < 64; ++k) {
    f32x4 w4 = wr[k];
    #pragma unroll
    for (int s = 0; s < 8; ++s) a[s] += dot4(w4, *(const f32x4*)&sl[s][k * 4]);
  }
  #pragma unroll
  for (int s = 0; s < 8; ++s) gq[(size_t)(b * 8 + s) * 256 + t] = a[s] * 0.0625f;   // SCALE folded
}

// ---------------- MFMA attention: dots + softmax(S) + P·V partials ----------------
// grid (CH, 64), block 256 (4 waves). Each block: 4096/CH n-rows in tiles of 64.
__global__ __launch_bounds__(256) void attn_kernel(
    const u16* __restrict__ kbuf, const u16* __restrict__ vtbuf,
    const float* __restrict__ gq, float* __restrict__ gUp, float* __restrict__ gdp)
{
  __shared__ __align__(16) u16 tb[256 * 72];      // union: k-tile [64][264] / vt-tile [256][72] / q fp32
  __shared__ __align__(16) u16 P[16 * 72];        // bf16 softmax weights, rows 8..15 zero
  __shared__ float wden[4][8];
  const int b = blockIdx.y, chunk = blockIdx.x;
  const int t = threadIdx.x;
  const int lane = t & 63, w = t >> 6;
  const int fr = lane & 15, fq = lane >> 4;
  const bool valid = fr < 8;

  // stage q (fp32) into tb, zero P rows 8..15
  {
    float* qs = (float*)tb;
    #pragma unroll
    for (int p = 0; p < 8; ++p) qs[t + p * 256] = gq[(size_t)b * 2048 + t + p * 256];
    u32* p32 = (u32*)P;
    if (t < 256) { p32[288 + t] = 0; if (t < 32) p32[544 + t] = 0; }   // u32 idx 288..575
  }
  __syncthreads();

  // build q bf16 fragments (registers, reused across all tiles)
  s16x8 qf[8];
  {
    const float* qs = (const float*)tb;
    if (valid) {
      #pragma unroll
      for (int ks = 0; ks < 8; ++ks) {
        f32x4 a = *(const f32x4*)&qs[fr * 256 + ks * 32 + fq * 8];
        f32x4 c = *(const f32x4*)&qs[fr * 256 + ks * 32 + fq * 8 + 4];
        s16x8 q8;
        q8[0] = (short)f2bf(a.x); q8[1] = (short)f2bf(a.y);
        q8[2] = (short)f2bf(a.z); q8[3] = (short)f2bf(a.w);
        q8[4] = (short)f2bf(c.x); q8[5] = (short)f2bf(c.y);
        q8[6] = (short)f2bf(c.z); q8[7] = (short)f2bf(c.w);
        qf[ks] = q8;
      }
    } else {
      #pragma unroll
      for (int ks = 0; ks < 8; ++ks) { s16x8 z = {0,0,0,0,0,0,0,0}; qf[ks] = z; }
    }
  }

  f32x4 uacc[4];
  #pragma unroll
  for (int ct = 0; ct < 4; ++ct) { f32x4 z = {0.f,0.f,0.f,0.f}; uacc[ct] = z; }
  float denom_loc = 0.f;

  for (int ti = 0; ti < GN / CH / 64; ++ti) {
    const int n0 = chunk * (GN / CH) + ti * 64;
    __syncthreads();                                   // prev tile fully consumed (incl. q staging)
    // stage k-tile [64][264]
    {
      const u16* kg = &kbuf[((size_t)b * 4096 + n0) * 256];
      #pragma unroll
      for (int p = 0; p < 8; ++p) {
        int q = t + p * 256;
        *(s16x8*)&tb[(q >> 5) * 264 + (q & 31) * 8] = *(const s16x8*)&kg[q * 8];
      }
    }
    __syncthreads();
    // dots: wave w -> n-rows w*16..+15; D[n][s]
    f32x4 dacc = {0.f, 0.f, 0.f, 0.f};
    #pragma unroll
    for (int ks = 0; ks < 8; ++ks) {
      s16x8 a = *(const s16x8*)&tb[(w * 16 + fr) * 264 + ks * 32 + fq * 8];
      dacc = __builtin_amdgcn_mfma_f32_16x16x32_bf16(a, qf[ks], dacc, 0, 0, 0);
    }
    // softmax over slot cols (s = fr), rows n = w*16 + fq*4 + r
    float pw[4];
    #pragma unroll
    for (int r = 0; r < 4; ++r) {
      float d = dacc[r];
      float m = d;
      #pragma unroll
      for (int msk = 1; msk < 8; msk <<= 1) m = fmaxf(m, __shfl_xor(m, msk, 64));
      float e = expf(d - m);
      float sm = e;
      #pragma unroll
      for (int msk = 1; msk < 8; msk <<= 1) sm += __shfl_xor(sm, msk, 64);
      pw[r] = e / sm + 1e-8f;
    }
    if (valid) {
      denom_loc += pw[0] + pw[1] + pw[2] + pw[3];
      u32 lo = (u32)f2bf(pw[0]) | ((u32)f2bf(pw[1]) << 16);
      u32 hi = (u32)f2bf(pw[2]) | ((u32)f2bf(pw[3]) << 16);
      *(u32*)&P[fr * 72 + w * 16 + fq * 4] = lo;
      *(u32*)&P[fr * 72 + w * 16 + fq * 4 + 2] = hi;
    }
    __syncthreads();                                   // k-tile reads done, P visible
    // stage vt-tile [256][72]
    {
      const u16* vg = &vtbuf[(size_t)(b * 64 + (n0 >> 6)) * 16384];
      #pragma unroll
      for (int p = 0; p < 8; ++p) {
        int q = t + p * 256;
        *(s16x8*)&tb[(q >> 3) * 72 + (q & 7) * 8] = *(const s16x8*)&vg[q * 8];
      }
    }
    __syncthreads();
    // update: U[s][d] += P[s][n] * V[n][d]; wave w -> d cols w*64..+63
    {
      s16x8 pa0 = *(const s16x8*)&P[fr * 72 + fq * 8];
      s16x8 pa1 = *(const s16x8*)&P[fr * 72 + 32 + fq * 8];
      #pragma unroll
      for (int ct = 0; ct < 4; ++ct) {
        s16x8 vb0 = *(const s16x8*)&tb[(w * 64 + ct * 16 + fr) * 72 + fq * 8];
        s16x8 vb1 = *(const s16x8*)&tb[(w * 64 + ct * 16 + fr) * 72 + 32 + fq * 8];
        uacc[ct] = __builtin_amdgcn_mfma_f32_16x16x32_bf16(pa0, vb0, uacc[ct], 0, 0, 0);
        uacc[ct] = __builtin_amdgcn_mfma_f32_16x16x32_bf16(pa1, vb1, uacc[ct], 0, 0, 0);
      }
    }
  }

  // denom: lanes sharing fr combine (fq bits), then cross-wave via LDS
  float dl = denom_loc;
  dl += __shfl_xor(dl, 16, 64);
  dl += __shfl_xor(dl, 32, 64);
  if (lane < 8) wden[w][lane] = dl;
  __syncthreads();
  if (t < 8) gdp[(chunk * 64 + b) * 8 + t] = wden[0][t] + wden[1][t] + wden[2][t] + wden[3][t];

  // U partials: lane<32 holds s = fq*4+r (0..7), d = w*64 + ct*16 + fr
  if (lane < 32) {
    size_t obase = (size_t)(chunk * 64 + b) * 8 * 256;
    #pragma unroll
    for (int ct = 0; ct < 4; ++ct)
      #pragma unroll
      for (int r = 0; r < 4; ++r)
        gUp[obase + (size_t)(fq * 4 + r) * 256 + w * 64 + ct * 16 + fr] = uacc[ct][r];
  }
}

// ---------------- updates/denom + GRU + LN + MLP residual ----------------
// grid: 128 blocks; block (bid>>1) = batch, (bid&1)*4 = first of 4 slots handled concurrently.
__global__ __launch_bounds__(256) void update_kernel(
    const float* __restrict__ gUp, const float* __restrict__ gdp,
    float* __restrict__ slots,
    const float* __restrict__ W_ih, const float* __restrict__ W_hh,
    const float* __restrict__ b_ih, const float* __restrict__ b_hh,
    const float* __restrict__ W1, const float* __restrict__ b1,
    const float* __restrict__ W2, const float* __restrict__ b2,
    const float* __restrict__ lng, const float* __restrict__ lnb,
    float* __restrict__ out, int last)
{
  __shared__ __align__(16) float us[1024];
  __shared__ __align__(16) float sp[1024];
  __shared__ __align__(16) float nl[1024];
  __shared__ __align__(16) float pl[1024];
  __shared__ __align__(16) float h1[2048];
  __shared__ float scr[8];
  const int bid = blockIdx.x;
  const int b = bid >> 1, s0 = (bid & 1) * 4;
  const int t = threadIdx.x;

  float spv[4];
  #pragma unroll
  for (int s = 0; s < 4; ++s) {
    int gsl = b * 8 + s0 + s;
    float dnm = 0.f, ua = 0.f;
    #pragma unroll 4
    for (int c = 0; c < CH; ++c) {
      dnm += gdp[(c * 64 + b) * 8 + s0 + s];
      ua += gUp[((size_t)(c * 64 + b) * 8 + s0 + s) * 256 + t];
    }
    us[s * 256 + t] = ua / dnm;
    float v = slots[gsl * 256 + t];
    sp[s * 256 + t] = v;
    spv[s] = v;
  }
  __syncthreads();

  // ---- GRU gates ----
  const f32x4* usv = (const f32x4*)us;
  const f32x4* spv4 = (const f32x4*)sp;
  float ax[3][4], ah[3][4];
  #pragma unroll
  for (int gi = 0; gi < 3; ++gi)
    #pragma unroll
    for (int s = 0; s < 4; ++s) { ax[gi][s] = 0.f; ah[gi][s] = 0.f; }
  #pragma unroll 2
  for (int k = 0; k < 64; ++k) {
    f32x4 wi[3], wh[3];
    #pragma unroll
    for (int gi = 0; gi < 3; ++gi) {
      wi[gi] = *(const f32x4*)&W_ih[(size_t)(gi * 256 + t) * 256 + k * 4];
      wh[gi] = *(const f32x4*)&W_hh[(size_t)(gi * 256 + t) * 256 + k * 4];
    }
    f32x4 uu[4], ss[4];
    #pragma unroll
    for (int s = 0; s < 4; ++s) { uu[s] = usv[s * 64 + k]; ss[s] = spv4[s * 64 + k]; }
    #pragma unroll
    for (int gi = 0; gi < 3; ++gi)
      #pragma unroll
      for (int s = 0; s < 4; ++s) {
        ax[gi][s] += dot4(wi[gi], uu[s]);
        ah[gi][s] += dot4(wh[gi], ss[s]);
      }
  }
  float bi0 = b_ih[t], bi1 = b_ih[t + 256], bi2 = b_ih[t + 512];
  float bh0 = b_hh[t], bh1 = b_hh[t + 256], bh2 = b_hh[t + 512];
  float news[4];
  #pragma unroll
  for (int s = 0; s < 4; ++s) {
    float r = 1.f / (1.f + expf(-(ax[0][s] + bi0 + ah[0][s] + bh0)));
    float z = 1.f / (1.f + expf(-(ax[1][s] + bi1 + ah[1][s] + bh1)));
    float nn = tanhf(ax[2][s] + bi2 + r * (ah[2][s] + bh2));
    news[s] = (1.f - z) * nn + z * spv[s];
    nl[s * 256 + t] = news[s];
  }
  __syncthreads();

  // ---- LN stats: wave w handles slot w ----
  {
    int wv = t >> 6, ln = t & 63;
    f32x4 v = *(const f32x4*)&nl[wv * 256 + ln * 4];
    float s1 = v.x + v.y + v.z + v.w;
    float s2 = v.x*v.x + v.y*v.y + v.z*v.z + v.w*v.w;
    #pragma unroll
    for (int m = 1; m < 64; m <<= 1) { s1 += __shfl_xor(s1, m, 64); s2 += __shfl_xor(s2, m, 64); }
    if (ln == 0) {
      float mu = s1 * (1.f / 256.f);
      float var = s2 * (1.f / 256.f) - mu * mu;
      scr[wv * 2] = mu;
      scr[wv * 2 + 1] = rsqrtf(var + 1e-3f);
    }
  }
  __syncthreads();
  float lg = lng[t], lb = lnb[t];
  #pragma unroll
  for (int s = 0; s < 4; ++s)
    pl[s * 256 + t] = (news[s] - scr[s * 2]) * scr[s * 2 + 1] * lg + lb;
  __syncthreads();

  // ---- MLP layer 1 ----
  const f32x4* plv = (const f32x4*)pl;
  {
    float a0[4], a1[4];
    #pragma unroll
    for (int s = 0; s < 4; ++s) { a0[s] = 0.f; a1[s] = 0.f; }
    #pragma unroll 2
    for (int k = 0; k < 64; ++k) {
      f32x4 wa = *(const f32x4*)&W1[(size_t)t * 256 + k * 4];
      f32x4 wb = *(const f32x4*)&W1[(size_t)(t + 256) * 256 + k * 4];
      #pragma unroll
      for (int s = 0; s < 4; ++s) {
        f32x4 pv = plv[s * 64 + k];
        a0[s] += dot4(wa, pv);
        a1[s] += dot4(wb, pv);
      }
    }
    float bb0 = b1[t], bb1 = b1[t + 256];
    #pragma unroll
    for (int s = 0; s < 4; ++s) {
      h1[s * 512 + t] = fmaxf(a0[s] + bb0, 0.f);
      h1[s * 512 + t + 256] = fmaxf(a1[s] + bb1, 0.f);
    }
  }
  __syncthreads();

  // ---- MLP layer 2 + residual ----
  const f32x4* h1v = (const f32x4*)h1;
  float o[4];
  #pragma unroll
  for (int s = 0; s < 4; ++s) o[s] = 0.f;
  #pragma unroll 2
  for (int k = 0; k < 128; ++k) {
    f32x4 w4 = *(const f32x4*)&W2[(size_t)t * 512 + k * 4];
    #pragma unroll
    for (int s = 0; s < 4; ++s)
      o[s] += dot4(w4, h1v[s * 128 + k]);
  }
  float bb2 = b2[t];
  #pragma unroll
  for (int s = 0; s < 4; ++s) {
    int gsl = b * 8 + s0 + s;
    float val = o[s] + news[s] + bb2;
    slots[gsl * 256 + t] = val;
    if (last) out[gsl * 256 + t] = val;
  }
}

extern "C" void kernel_launch(void* const* d_in, const int* in_sizes, int n_in,
                              void* d_out, int out_size, void* d_ws, size_t ws_size,
                              hipStream_t stream) {
  const float* inputs   = (const float*)d_in[0];
  const float* noise    = (const float*)d_in[1];
  const float* slots_mu = (const float*)d_in[2];
  const float* slots_ls = (const float*)d_in[3];
  const float* Wq   = (const float*)d_in[4];
  const float* Wk   = (const float*)d_in[5];
  const float* Wv   = (const float*)d_in[6];
  const float* W_ih = (const float*)d_in[7];
  const float* W_hh = (const float*)d_in[8];
  const float* b_ih = (const float*)d_in[9];
  const float* b_hh = (const float*)d_in[10];
  const float* W1   = (const float*)d_in[11];
  const float* b1   = (const float*)d_in[12];
  const float* W2   = (const float*)d_in[13];
  const float* b2   = (const float*)d_in[14];
  const float* ln_in_g = (const float*)d_in[15];
  const float* ln_in_b = (const float*)d_in[16];
  const float* ln_s_g  = (const float*)d_in[17];
  const float* ln_s_b  = (const float*)d_in[18];
  const float* ln_ff_g = (const float*)d_in[19];
  const float* ln_ff_b = (const float*)d_in[20];
  float* out = (float*)d_out;

  char* w = (char*)d_ws;
  u16* kbuf = (u16*)w;     w += (size_t)GM * 256 * 2;        // 128 MB
  u16* vtbuf = (u16*)w;    w += (size_t)GM * 256 * 2;        // 128 MB (tiled transposed)
  u16* wkv = (u16*)w;      w += (size_t)512 * 256 * 2;       // 256 KB
  float* slots = (float*)w; w += (size_t)131072 * 4;
  float* gq = (float*)w;    w += (size_t)131072 * 4;
  float* gUp = (float*)w;   w += (size_t)CH * 64 * 8 * 256 * 4;   // 8 MB
  float* gdp = (float*)w;   w += (size_t)CH * 64 * 8 * 4;         // 32 KB

  init_slots_kernel<<<512, 256, 0, stream>>>(noise, slots_mu, slots_ls, slots);
  wconv_kernel<<<256, 256, 0, stream>>>(Wk, Wv, wkv);
  gemm_kv<<<GM / 64, 512, 0, stream>>>(inputs, wkv, ln_in_g, ln_in_b, kbuf, vtbuf);

  for (int it = 0; it < 3; ++it) {
    qproj_kernel<<<64, 256, 0, stream>>>(slots, Wq, ln_s_g, ln_s_b, gq);
    attn_kernel<<<dim3(CH, 64), 256, 0, stream>>>(kbuf, vtbuf, gq, gUp, gdp);
    update_kernel<<<128, 256, 0, stream>>>(gUp, gdp, slots, W_ih, W_hh, b_ih, b_hh,
                                           W1, b1, W2, b2, ln_ff_g, ln_ff_b, out, it == 2);
  }
}

// Round 4
// 854.881 us; speedup vs baseline: 1.0793x; 1.0793x over previous
//
#include <hip/hip_runtime.h>

typedef unsigned short u16;
typedef unsigned int u32;
typedef __attribute__((ext_vector_type(4))) float f32x4;
typedef __attribute__((ext_vector_type(8))) short s16x8;

#define GM 262144   // B*N rows
#define GB 64
#define GN 4096
#define GC 256
#define GD 256
#define GS 8
#define GH 512
#define CH 16       // attn chunks per batch

#define GLDS16(G, L) __builtin_amdgcn_global_load_lds( \
    (const __attribute__((address_space(1))) void*)(G), \
    (__attribute__((address_space(3))) void*)(L), 16, 0, 0)

__device__ __forceinline__ float bf2f(u16 u) {
  union { unsigned int i; float f; } c; c.i = ((unsigned int)u) << 16; return c.f;
}
__device__ __forceinline__ u16 f2bf(float f) {
  union { float f; unsigned int i; } c; c.f = f;
  unsigned int x = c.i;
  unsigned int r = x + 0x7FFFu + ((x >> 16) & 1u);
  return (u16)(r >> 16);
}
__device__ __forceinline__ float dot4(f32x4 a, f32x4 b) {
  return a.x*b.x + a.y*b.y + a.z*b.z + a.w*b.w;
}

// ---------------- slots init: mu + exp(log_sigma)*noise ----------------
__global__ void init_slots_kernel(const float* __restrict__ noise, const float* __restrict__ smu,
                                  const float* __restrict__ sls, float* __restrict__ slots)
{
  int i = blockIdx.x * 256 + threadIdx.x;   // 131072 total
  int d = i & 255;
  slots[i] = smu[d] + expf(sls[d]) * noise[i];
}

// ---------------- weight convert fp32->bf16 (Wk rows 0..255, Wv rows 256..511) ----------------
__global__ void wconv_kernel(const float* __restrict__ Wk, const float* __restrict__ Wv, u16* __restrict__ wkv)
{
  int i = blockIdx.x * 256 + threadIdx.x;   // 65536
  wkv[i] = f2bf(Wk[i]);
  wkv[i + 65536] = f2bf(Wv[i]);
}

// ---------------- LN(inputs) -> bf16 xbuf (memory-bound, one pass) ----------------
// one wave per row; lane holds 4 cols.
__global__ __launch_bounds__(256) void ln_bf16_kernel(
    const float* __restrict__ x, const float* __restrict__ g, const float* __restrict__ be,
    u16* __restrict__ xbuf)
{
  int row = blockIdx.x * 4 + (threadIdx.x >> 6);
  int lane = threadIdx.x & 63;
  f32x4 v = *(const f32x4*)&x[(size_t)row * 256 + lane * 4];
  float s = v.x + v.y + v.z + v.w;
  float sq = v.x*v.x + v.y*v.y + v.z*v.z + v.w*v.w;
  #pragma unroll
  for (int m = 1; m < 64; m <<= 1) { s += __shfl_xor(s, m, 64); sq += __shfl_xor(sq, m, 64); }
  float mu = s * (1.f / 256.f);
  float var = sq * (1.f / 256.f) - mu * mu;
  float rstd = rsqrtf(var + 1e-3f);
  f32x4 gv = *(const f32x4*)&g[lane * 4];
  f32x4 bv = *(const f32x4*)&be[lane * 4];
  uint2 pk;
  pk.x = (u32)f2bf((v.x - mu) * rstd * gv.x + bv.x)
       | ((u32)f2bf((v.y - mu) * rstd * gv.y + bv.y) << 16);
  pk.y = (u32)f2bf((v.z - mu) * rstd * gv.z + bv.z)
       | ((u32)f2bf((v.w - mu) * rstd * gv.w + bv.w) << 16);
  *(uint2*)&xbuf[(size_t)row * 256 + lane * 4] = pk;
}

// ---------------- K/V projection GEMM (m97-style: global_load_lds staging) ----------------
// grid (2048, 4): 128-row tile x 128-col tile; cb 0,1 -> K cols, cb 2,3 -> V cols (transposed out).
// block 256 thr = 4 waves (2x2), each wave 64x64, acc[4][4], BK=32, 8 k-steps.
__global__ __launch_bounds__(256) void gemm_kv(
    const u16* __restrict__ xbuf, const u16* __restrict__ wkv,
    u16* __restrict__ kbuf, u16* __restrict__ vtbuf)
{
  __shared__ __align__(16) u16 As[128 * 32];
  __shared__ __align__(16) u16 Bs[128 * 32];
  const int t = threadIdx.x;
  const int brow = blockIdx.x * 128;
  const int cb = blockIdx.y;
  const int bcol = cb * 128;
  const int lane = t & 63, w = t >> 6;
  const int wr = w >> 1, wc = w & 1;
  const int fr = lane & 15, fq = lane >> 4;

  const u16* aTile = xbuf + (size_t)brow * 256;
  const u16* bTile = wkv + (size_t)bcol * 256;
  u16* asBase = &As[w * 1024];        // wave-uniform LDS dest (u16 units)
  u16* bsBase = &Bs[w * 1024];

  f32x4 acc[4][4];
  #pragma unroll
  for (int i = 0; i < 4; ++i)
    #pragma unroll
    for (int j = 0; j < 4; ++j) { f32x4 z = {0.f,0.f,0.f,0.f}; acc[i][j] = z; }

  for (int kk = 0; kk < 256; kk += 32) {
    __syncthreads();                  // previous frag reads complete before overwrite
    #pragma unroll
    for (int p = 0; p < 2; ++p) {
      int u = w * 1024 + p * 512 + lane * 8;     // u16 index into 128x32 tile
      int row = u >> 5, col = u & 31;
      GLDS16(aTile + (size_t)row * 256 + kk + col, asBase + p * 512);
      GLDS16(bTile + (size_t)row * 256 + kk + col, bsBase + p * 512);
    }
    asm volatile("s_waitcnt vmcnt(0)");
    __syncthreads();
    s16x8 af[4], bf[4];
    #pragma unroll
    for (int i = 0; i < 4; ++i) af[i] = *(const s16x8*)&As[(wr * 64 + i * 16 + fr) * 32 + fq * 8];
    #pragma unroll
    for (int j = 0; j < 4; ++j) bf[j] = *(const s16x8*)&Bs[(wc * 64 + j * 16 + fr) * 32 + fq * 8];
    #pragma unroll
    for (int i = 0; i < 4; ++i)
      #pragma unroll
      for (int j = 0; j < 4; ++j)
        acc[i][j] = __builtin_amdgcn_mfma_f32_16x16x32_bf16(af[i], bf[j], acc[i][j], 0, 0, 0);
  }

  if (cb < 2) {
    #pragma unroll
    for (int i = 0; i < 4; ++i)
      #pragma unroll
      for (int j = 0; j < 4; ++j)
        #pragma unroll
        for (int r = 0; r < 4; ++r)
          kbuf[(size_t)(brow + wr * 64 + i * 16 + fq * 4 + r) * 256 + bcol + wc * 64 + j * 16 + fr]
              = f2bf(acc[i][j][r]);
  } else {
    // V transposed tiles: vtbuf[ntile][d][64], ntile = global_row >> 6
    size_t base = (size_t)((brow + wr * 64) >> 6) * 16384;
    #pragma unroll
    for (int i = 0; i < 4; ++i)
      #pragma unroll
      for (int j = 0; j < 4; ++j)
        #pragma unroll
        for (int r = 0; r < 4; ++r)
          vtbuf[base + (size_t)(bcol - 256 + wc * 64 + j * 16 + fr) * 64 + i * 16 + fq * 4 + r]
              = f2bf(acc[i][j][r]);
  }
}

// ---------------- slot LN + q projection, all 8 slots per batch in one block ----------------
__global__ __launch_bounds__(256) void qproj_kernel(const float* __restrict__ slots, const float* __restrict__ Wq,
    const float* __restrict__ g, const float* __restrict__ be, float* __restrict__ gq)
{
  __shared__ __align__(16) float sl[8][256];
  int b = blockIdx.x, t = threadIdx.x;
  int lane = t & 63, w = t >> 6;
  #pragma unroll
  for (int s2 = 0; s2 < 2; ++s2) {
    int s = w * 2 + s2;
    f32x4 v = *(const f32x4*)&slots[(size_t)(b * 8 + s) * 256 + lane * 4];
    float s1 = v.x + v.y + v.z + v.w;
    float q1 = v.x*v.x + v.y*v.y + v.z*v.z + v.w*v.w;
    #pragma unroll
    for (int m = 1; m < 64; m <<= 1) { s1 += __shfl_xor(s1, m, 64); q1 += __shfl_xor(q1, m, 64); }
    float mu = s1 * (1.f / 256.f);
    float var = q1 * (1.f / 256.f) - mu * mu;
    float rstd = rsqrtf(var + 1e-3f);
    f32x4 gv = *(const f32x4*)&g[lane * 4];
    f32x4 bv = *(const f32x4*)&be[lane * 4];
    f32x4 o;
    o.x = (v.x - mu) * rstd * gv.x + bv.x;
    o.y = (v.y - mu) * rstd * gv.y + bv.y;
    o.z = (v.z - mu) * rstd * gv.z + bv.z;
    o.w = (v.w - mu) * rstd * gv.w + bv.w;
    *(f32x4*)&sl[s][lane * 4] = o;
  }
  __syncthreads();
  float a[8];
  #pragma unroll
  for (int s = 0; s < 8; ++s) a[s] = 0.f;
  const f32x4* wr = (const f32x4*)&Wq[(size_t)t * 256];
  for (int k = 0; k < 64; ++k) {
    f32x4 w4 = wr[k];
    #pragma unroll
    for (int s = 0; s < 8; ++s) a[s] += dot4(w4, *(const f32x4*)&sl[s][k * 4]);
  }
  #pragma unroll
  for (int s = 0; s < 8; ++s) gq[(size_t)(b * 8 + s) * 256 + t] = a[s] * 0.0625f;   // SCALE folded
}

// ---------------- MFMA attention: dots + softmax(S) + P·V partials ----------------
// grid (CH, 64), block 256 (4 waves). Each block: 4096/CH n-rows in tiles of 64.
__global__ __launch_bounds__(256) void attn_kernel(
    const u16* __restrict__ kbuf, const u16* __restrict__ vtbuf,
    const float* __restrict__ gq, float* __restrict__ gUp, float* __restrict__ gdp)
{
  __shared__ __align__(16) u16 tb[256 * 72];      // union: k-tile [64][264] / vt-tile [256][72] / q fp32
  __shared__ __align__(16) u16 P[16 * 72];        // bf16 softmax weights, rows 8..15 zero
  __shared__ float wden[4][8];
  const int b = blockIdx.y, chunk = blockIdx.x;
  const int t = threadIdx.x;
  const int lane = t & 63, w = t >> 6;
  const int fr = lane & 15, fq = lane >> 4;
  const bool valid = fr < 8;

  // stage q (fp32) into tb, zero P rows 8..15
  {
    float* qs = (float*)tb;
    #pragma unroll
    for (int p = 0; p < 8; ++p) qs[t + p * 256] = gq[(size_t)b * 2048 + t + p * 256];
    u32* p32 = (u32*)P;
    if (t < 256) { p32[288 + t] = 0; if (t < 32) p32[544 + t] = 0; }   // u32 idx 288..575
  }
  __syncthreads();

  // build q bf16 fragments (registers, reused across all tiles)
  s16x8 qf[8];
  {
    const float* qs = (const float*)tb;
    if (valid) {
      #pragma unroll
      for (int ks = 0; ks < 8; ++ks) {
        f32x4 a = *(const f32x4*)&qs[fr * 256 + ks * 32 + fq * 8];
        f32x4 c = *(const f32x4*)&qs[fr * 256 + ks * 32 + fq * 8 + 4];
        s16x8 q8;
        q8[0] = (short)f2bf(a.x); q8[1] = (short)f2bf(a.y);
        q8[2] = (short)f2bf(a.z); q8[3] = (short)f2bf(a.w);
        q8[4] = (short)f2bf(c.x); q8[5] = (short)f2bf(c.y);
        q8[6] = (short)f2bf(c.z); q8[7] = (short)f2bf(c.w);
        qf[ks] = q8;
      }
    } else {
      #pragma unroll
      for (int ks = 0; ks < 8; ++ks) { s16x8 z = {0,0,0,0,0,0,0,0}; qf[ks] = z; }
    }
  }

  f32x4 uacc[4];
  #pragma unroll
  for (int ct = 0; ct < 4; ++ct) { f32x4 z = {0.f,0.f,0.f,0.f}; uacc[ct] = z; }
  float denom_loc = 0.f;

  for (int ti = 0; ti < GN / CH / 64; ++ti) {
    const int n0 = chunk * (GN / CH) + ti * 64;
    __syncthreads();                                   // prev tile fully consumed (incl. q staging)
    // stage k-tile [64][264]
    {
      const u16* kg = &kbuf[((size_t)b * 4096 + n0) * 256];
      #pragma unroll
      for (int p = 0; p < 8; ++p) {
        int q = t + p * 256;
        *(s16x8*)&tb[(q >> 5) * 264 + (q & 31) * 8] = *(const s16x8*)&kg[q * 8];
      }
    }
    __syncthreads();
    // dots: wave w -> n-rows w*16..+15; D[n][s]
    f32x4 dacc = {0.f, 0.f, 0.f, 0.f};
    #pragma unroll
    for (int ks = 0; ks < 8; ++ks) {
      s16x8 a = *(const s16x8*)&tb[(w * 16 + fr) * 264 + ks * 32 + fq * 8];
      dacc = __builtin_amdgcn_mfma_f32_16x16x32_bf16(a, qf[ks], dacc, 0, 0, 0);
    }
    // softmax over slot cols (s = fr), rows n = w*16 + fq*4 + r
    float pw[4];
    #pragma unroll
    for (int r = 0; r < 4; ++r) {
      float d = dacc[r];
      float m = d;
      #pragma unroll
      for (int msk = 1; msk < 8; msk <<= 1) m = fmaxf(m, __shfl_xor(m, msk, 64));
      float e = expf(d - m);
      float sm = e;
      #pragma unroll
      for (int msk = 1; msk < 8; msk <<= 1) sm += __shfl_xor(sm, msk, 64);
      pw[r] = e / sm + 1e-8f;
    }
    if (valid) {
      denom_loc += pw[0] + pw[1] + pw[2] + pw[3];
      u32 lo = (u32)f2bf(pw[0]) | ((u32)f2bf(pw[1]) << 16);
      u32 hi = (u32)f2bf(pw[2]) | ((u32)f2bf(pw[3]) << 16);
      *(u32*)&P[fr * 72 + w * 16 + fq * 4] = lo;
      *(u32*)&P[fr * 72 + w * 16 + fq * 4 + 2] = hi;
    }
    __syncthreads();                                   // k-tile reads done, P visible
    // stage vt-tile [256][72]
    {
      const u16* vg = &vtbuf[(size_t)(b * 64 + (n0 >> 6)) * 16384];
      #pragma unroll
      for (int p = 0; p < 8; ++p) {
        int q = t + p * 256;
        *(s16x8*)&tb[(q >> 3) * 72 + (q & 7) * 8] = *(const s16x8*)&vg[q * 8];
      }
    }
    __syncthreads();
    // update: U[s][d] += P[s][n] * V[n][d]; wave w -> d cols w*64..+63
    {
      s16x8 pa0 = *(const s16x8*)&P[fr * 72 + fq * 8];
      s16x8 pa1 = *(const s16x8*)&P[fr * 72 + 32 + fq * 8];
      #pragma unroll
      for (int ct = 0; ct < 4; ++ct) {
        s16x8 vb0 = *(const s16x8*)&tb[(w * 64 + ct * 16 + fr) * 72 + fq * 8];
        s16x8 vb1 = *(const s16x8*)&tb[(w * 64 + ct * 16 + fr) * 72 + 32 + fq * 8];
        uacc[ct] = __builtin_amdgcn_mfma_f32_16x16x32_bf16(pa0, vb0, uacc[ct], 0, 0, 0);
        uacc[ct] = __builtin_amdgcn_mfma_f32_16x16x32_bf16(pa1, vb1, uacc[ct], 0, 0, 0);
      }
    }
  }

  // denom: lanes sharing fr combine (fq bits), then cross-wave via LDS
  float dl = denom_loc;
  dl += __shfl_xor(dl, 16, 64);
  dl += __shfl_xor(dl, 32, 64);
  if (lane < 8) wden[w][lane] = dl;
  __syncthreads();
  if (t < 8) gdp[(chunk * 64 + b) * 8 + t] = wden[0][t] + wden[1][t] + wden[2][t] + wden[3][t];

  // U partials: lane<32 holds s = fq*4+r (0..7), d = w*64 + ct*16 + fr
  if (lane < 32) {
    size_t obase = (size_t)(chunk * 64 + b) * 8 * 256;
    #pragma unroll
    for (int ct = 0; ct < 4; ++ct)
      #pragma unroll
      for (int r = 0; r < 4; ++r)
        gUp[obase + (size_t)(fq * 4 + r) * 256 + w * 64 + ct * 16 + fr] = uacc[ct][r];
  }
}

// ---------------- updates/denom + GRU + LN + MLP residual ----------------
// grid: 128 blocks; block (bid>>1) = batch, (bid&1)*4 = first of 4 slots handled concurrently.
__global__ __launch_bounds__(256) void update_kernel(
    const float* __restrict__ gUp, const float* __restrict__ gdp,
    float* __restrict__ slots,
    const float* __restrict__ W_ih, const float* __restrict__ W_hh,
    const float* __restrict__ b_ih, const float* __restrict__ b_hh,
    const float* __restrict__ W1, const float* __restrict__ b1,
    const float* __restrict__ W2, const float* __restrict__ b2,
    const float* __restrict__ lng, const float* __restrict__ lnb,
    float* __restrict__ out, int last)
{
  __shared__ __align__(16) float us[1024];
  __shared__ __align__(16) float sp[1024];
  __shared__ __align__(16) float nl[1024];
  __shared__ __align__(16) float pl[1024];
  __shared__ __align__(16) float h1[2048];
  __shared__ float scr[8];
  const int bid = blockIdx.x;
  const int b = bid >> 1, s0 = (bid & 1) * 4;
  const int t = threadIdx.x;

  float spv[4];
  #pragma unroll
  for (int s = 0; s < 4; ++s) {
    int gsl = b * 8 + s0 + s;
    float dnm = 0.f, ua = 0.f;
    #pragma unroll 4
    for (int c = 0; c < CH; ++c) {
      dnm += gdp[(c * 64 + b) * 8 + s0 + s];
      ua += gUp[((size_t)(c * 64 + b) * 8 + s0 + s) * 256 + t];
    }
    us[s * 256 + t] = ua / dnm;
    float v = slots[gsl * 256 + t];
    sp[s * 256 + t] = v;
    spv[s] = v;
  }
  __syncthreads();

  // ---- GRU gates ----
  const f32x4* usv = (const f32x4*)us;
  const f32x4* spv4 = (const f32x4*)sp;
  float ax[3][4], ah[3][4];
  #pragma unroll
  for (int gi = 0; gi < 3; ++gi)
    #pragma unroll
    for (int s = 0; s < 4; ++s) { ax[gi][s] = 0.f; ah[gi][s] = 0.f; }
  #pragma unroll 2
  for (int k = 0; k < 64; ++k) {
    f32x4 wi[3], wh[3];
    #pragma unroll
    for (int gi = 0; gi < 3; ++gi) {
      wi[gi] = *(const f32x4*)&W_ih[(size_t)(gi * 256 + t) * 256 + k * 4];
      wh[gi] = *(const f32x4*)&W_hh[(size_t)(gi * 256 + t) * 256 + k * 4];
    }
    f32x4 uu[4], ss[4];
    #pragma unroll
    for (int s = 0; s < 4; ++s) { uu[s] = usv[s * 64 + k]; ss[s] = spv4[s * 64 + k]; }
    #pragma unroll
    for (int gi = 0; gi < 3; ++gi)
      #pragma unroll
      for (int s = 0; s < 4; ++s) {
        ax[gi][s] += dot4(wi[gi], uu[s]);
        ah[gi][s] += dot4(wh[gi], ss[s]);
      }
  }
  float bi0 = b_ih[t], bi1 = b_ih[t + 256], bi2 = b_ih[t + 512];
  float bh0 = b_hh[t], bh1 = b_hh[t + 256], bh2 = b_hh[t + 512];
  float news[4];
  #pragma unroll
  for (int s = 0; s < 4; ++s) {
    float r = 1.f / (1.f + expf(-(ax[0][s] + bi0 + ah[0][s] + bh0)));
    float z = 1.f / (1.f + expf(-(ax[1][s] + bi1 + ah[1][s] + bh1)));
    float nn = tanhf(ax[2][s] + bi2 + r * (ah[2][s] + bh2));
    news[s] = (1.f - z) * nn + z * spv[s];
    nl[s * 256 + t] = news[s];
  }
  __syncthreads();

  // ---- LN stats: wave w handles slot w ----
  {
    int wv = t >> 6, ln = t & 63;
    f32x4 v = *(const f32x4*)&nl[wv * 256 + ln * 4];
    float s1 = v.x + v.y + v.z + v.w;
    float s2 = v.x*v.x + v.y*v.y + v.z*v.z + v.w*v.w;
    #pragma unroll
    for (int m = 1; m < 64; m <<= 1) { s1 += __shfl_xor(s1, m, 64); s2 += __shfl_xor(s2, m, 64); }
    if (ln == 0) {
      float mu = s1 * (1.f / 256.f);
      float var = s2 * (1.f / 256.f) - mu * mu;
      scr[wv * 2] = mu;
      scr[wv * 2 + 1] = rsqrtf(var + 1e-3f);
    }
  }
  __syncthreads();
  float lg = lng[t], lb = lnb[t];
  #pragma unroll
  for (int s = 0; s < 4; ++s)
    pl[s * 256 + t] = (news[s] - scr[s * 2]) * scr[s * 2 + 1] * lg + lb;
  __syncthreads();

  // ---- MLP layer 1 ----
  const f32x4* plv = (const f32x4*)pl;
  {
    float a0[4], a1[4];
    #pragma unroll
    for (int s = 0; s < 4; ++s) { a0[s] = 0.f; a1[s] = 0.f; }
    #pragma unroll 2
    for (int k = 0; k < 64; ++k) {
      f32x4 wa = *(const f32x4*)&W1[(size_t)t * 256 + k * 4];
      f32x4 wb = *(const f32x4*)&W1[(size_t)(t + 256) * 256 + k * 4];
      #pragma unroll
      for (int s = 0; s < 4; ++s) {
        f32x4 pv = plv[s * 64 + k];
        a0[s] += dot4(wa, pv);
        a1[s] += dot4(wb, pv);
      }
    }
    float bb0 = b1[t], bb1 = b1[t + 256];
    #pragma unroll
    for (int s = 0; s < 4; ++s) {
      h1[s * 512 + t] = fmaxf(a0[s] + bb0, 0.f);
      h1[s * 512 + t + 256] = fmaxf(a1[s] + bb1, 0.f);
    }
  }
  __syncthreads();

  // ---- MLP layer 2 + residual ----
  const f32x4* h1v = (const f32x4*)h1;
  float o[4];
  #pragma unroll
  for (int s = 0; s < 4; ++s) o[s] = 0.f;
  #pragma unroll 2
  for (int k = 0; k < 128; ++k) {
    f32x4 w4 = *(const f32x4*)&W2[(size_t)t * 512 + k * 4];
    #pragma unroll
    for (int s = 0; s < 4; ++s)
      o[s] += dot4(w4, h1v[s * 128 + k]);
  }
  float bb2 = b2[t];
  #pragma unroll
  for (int s = 0; s < 4; ++s) {
    int gsl = b * 8 + s0 + s;
    float val = o[s] + news[s] + bb2;
    slots[gsl * 256 + t] = val;
    if (last) out[gsl * 256 + t] = val;
  }
}

extern "C" void kernel_launch(void* const* d_in, const int* in_sizes, int n_in,
                              void* d_out, int out_size, void* d_ws, size_t ws_size,
                              hipStream_t stream) {
  const float* inputs   = (const float*)d_in[0];
  const float* noise    = (const float*)d_in[1];
  const float* slots_mu = (const float*)d_in[2];
  const float* slots_ls = (const float*)d_in[3];
  const float* Wq   = (const float*)d_in[4];
  const float* Wk   = (const float*)d_in[5];
  const float* Wv   = (const float*)d_in[6];
  const float* W_ih = (const float*)d_in[7];
  const float* W_hh = (const float*)d_in[8];
  const float* b_ih = (const float*)d_in[9];
  const float* b_hh = (const float*)d_in[10];
  const float* W1   = (const float*)d_in[11];
  const float* b1   = (const float*)d_in[12];
  const float* W2   = (const float*)d_in[13];
  const float* b2   = (const float*)d_in[14];
  const float* ln_in_g = (const float*)d_in[15];
  const float* ln_in_b = (const float*)d_in[16];
  const float* ln_s_g  = (const float*)d_in[17];
  const float* ln_s_b  = (const float*)d_in[18];
  const float* ln_ff_g = (const float*)d_in[19];
  const float* ln_ff_b = (const float*)d_in[20];
  float* out = (float*)d_out;

  char* w = (char*)d_ws;
  // region0: xbuf (alive: ln_bf16 -> gemm) overlays gUp/gdp (alive: attn -> update)
  u16* xbuf = (u16*)w;
  float* gUp = (float*)w;
  float* gdp = (float*)(w + (size_t)CH * 64 * 8 * 256 * 4);
  w += (size_t)GM * 256 * 2;                                  // 128 MB (xbuf; gUp+gdp use 8.03 MB of it)
  u16* kbuf = (u16*)w;     w += (size_t)GM * 256 * 2;         // 128 MB
  u16* vtbuf = (u16*)w;    w += (size_t)GM * 256 * 2;         // 128 MB (tiled transposed)
  u16* wkv = (u16*)w;      w += (size_t)512 * 256 * 2;        // 256 KB
  float* slots = (float*)w; w += (size_t)131072 * 4;
  float* gq = (float*)w;    w += (size_t)131072 * 4;

  init_slots_kernel<<<512, 256, 0, stream>>>(noise, slots_mu, slots_ls, slots);
  wconv_kernel<<<256, 256, 0, stream>>>(Wk, Wv, wkv);
  ln_bf16_kernel<<<GM / 4, 256, 0, stream>>>(inputs, ln_in_g, ln_in_b, xbuf);
  gemm_kv<<<dim3(GM / 128, 4), 256, 0, stream>>>(xbuf, wkv, kbuf, vtbuf);

  for (int it = 0; it < 3; ++it) {
    qproj_kernel<<<64, 256, 0, stream>>>(slots, Wq, ln_s_g, ln_s_b, gq);
    attn_kernel<<<dim3(CH, 64), 256, 0, stream>>>(kbuf, vtbuf, gq, gUp, gdp);
    update_kernel<<<128, 256, 0, stream>>>(gUp, gdp, slots, W_ih, W_hh, b_ih, b_hh,
                                           W1, b1, W2, b2, ln_ff_g, ln_ff_b, out, it == 2);
  }
}

// Round 5
// 776.163 us; speedup vs baseline: 1.1888x; 1.1014x over previous
//
#include <hip/hip_runtime.h>

typedef unsigned short u16;
typedef unsigned int u32;
typedef __attribute__((ext_vector_type(4))) float f32x4;
typedef __attribute__((ext_vector_type(8))) short s16x8;

#define GM 262144   // B*N rows
#define GB 64
#define GN 4096
#define GC 256
#define GD 256
#define GS 8
#define GH 512
#define CH 16       // attn chunks per batch

#define GLDS16(G, L) __builtin_amdgcn_global_load_lds( \
    (const __attribute__((address_space(1))) void*)(G), \
    (__attribute__((address_space(3))) void*)(L), 16, 0, 0)

__device__ __forceinline__ float bf2f(u16 u) {
  union { unsigned int i; float f; } c; c.i = ((unsigned int)u) << 16; return c.f;
}
__device__ __forceinline__ u16 f2bf(float f) {
  union { float f; unsigned int i; } c; c.f = f;
  unsigned int x = c.i;
  unsigned int r = x + 0x7FFFu + ((x >> 16) & 1u);
  return (u16)(r >> 16);
}
__device__ __forceinline__ float dot4(f32x4 a, f32x4 b) {
  return a.x*b.x + a.y*b.y + a.z*b.z + a.w*b.w;
}

// ---------------- slots init ----------------
__global__ void init_slots_kernel(const float* __restrict__ noise, const float* __restrict__ smu,
                                  const float* __restrict__ sls, float* __restrict__ slots)
{
  int i = blockIdx.x * 256 + threadIdx.x;
  int d = i & 255;
  slots[i] = smu[d] + expf(sls[d]) * noise[i];
}

// ---------------- weight prep: wkv, Wcat (gates), W1b, W2b all bf16 ----------------
// Wcat rows: [0,512) = [Wih_r,z | Whh_r,z]; [512,768) = [Wih_n | 0]; [768,1024) = [0 | Whh_n]
__global__ void wprep_kernel(const float* __restrict__ Wk, const float* __restrict__ Wv,
                             const float* __restrict__ Wih, const float* __restrict__ Whh,
                             const float* __restrict__ W1, const float* __restrict__ W2,
                             u16* __restrict__ wkv, u16* __restrict__ Wcat,
                             u16* __restrict__ W1b, u16* __restrict__ W2b)
{
  int i = blockIdx.x * 256 + threadIdx.x;       // 917504 total
  if (i < 131072) {
    wkv[i] = f2bf(i < 65536 ? Wk[i] : Wv[i - 65536]);
  } else if (i < 655360) {
    int j2 = i - 131072;
    int r = j2 >> 9, k = j2 & 511;
    float v;
    if (r < 512)      v = (k < 256) ? Wih[r * 256 + k] : Whh[r * 256 + (k - 256)];
    else if (r < 768) v = (k < 256) ? Wih[r * 256 + k] : 0.f;
    else              v = (k < 256) ? 0.f : Whh[(r - 256) * 256 + (k - 256)];
    Wcat[j2] = f2bf(v);
  } else if (i < 786432) {
    int j2 = i - 655360;
    W1b[j2] = f2bf(W1[j2]);
  } else {
    int j2 = i - 786432;
    W2b[j2] = f2bf(W2[j2]);
  }
}

// ---------------- LN(inputs) -> bf16 xbuf ----------------
__global__ __launch_bounds__(256) void ln_bf16_kernel(
    const float* __restrict__ x, const float* __restrict__ g, const float* __restrict__ be,
    u16* __restrict__ xbuf)
{
  int row = blockIdx.x * 4 + (threadIdx.x >> 6);
  int lane = threadIdx.x & 63;
  f32x4 v = *(const f32x4*)&x[(size_t)row * 256 + lane * 4];
  float s = v.x + v.y + v.z + v.w;
  float sq = v.x*v.x + v.y*v.y + v.z*v.z + v.w*v.w;
  #pragma unroll
  for (int m = 1; m < 64; m <<= 1) { s += __shfl_xor(s, m, 64); sq += __shfl_xor(sq, m, 64); }
  float mu = s * (1.f / 256.f);
  float var = sq * (1.f / 256.f) - mu * mu;
  float rstd = rsqrtf(var + 1e-3f);
  f32x4 gv = *(const f32x4*)&g[lane * 4];
  f32x4 bv = *(const f32x4*)&be[lane * 4];
  uint2 pk;
  pk.x = (u32)f2bf((v.x - mu) * rstd * gv.x + bv.x)
       | ((u32)f2bf((v.y - mu) * rstd * gv.y + bv.y) << 16);
  pk.y = (u32)f2bf((v.z - mu) * rstd * gv.z + bv.z)
       | ((u32)f2bf((v.w - mu) * rstd * gv.w + bv.w) << 16);
  *(uint2*)&xbuf[(size_t)row * 256 + lane * 4] = pk;
}

// ---------------- K/V projection GEMM: BK=64, both-sides XOR swizzle ----------------
// grid (2048, 4): 128-row x 128-col tiles; cb 0,1 -> K, cb 2,3 -> V (transposed out).
__global__ __launch_bounds__(256) void gemm_kv(
    const u16* __restrict__ xbuf, const u16* __restrict__ wkv,
    u16* __restrict__ kbuf, u16* __restrict__ vtbuf)
{
  __shared__ __align__(16) u16 As[128 * 64];
  __shared__ __align__(16) u16 Bs[128 * 64];
  const int t = threadIdx.x;
  const int brow = blockIdx.x * 128;
  const int cb = blockIdx.y;
  const int bcol = cb * 128;
  const int lane = t & 63, w = t >> 6;
  const int wr = w >> 1, wc = w & 1;
  const int fr = lane & 15, fq = lane >> 4;
  const int sx = fr & 7;

  const u16* aTile = xbuf + (size_t)brow * 256;
  const u16* bTile = wkv + (size_t)bcol * 256;

  f32x4 acc[4][4];
  #pragma unroll
  for (int i = 0; i < 4; ++i)
    #pragma unroll
    for (int j = 0; j < 4; ++j) { f32x4 z = {0.f,0.f,0.f,0.f}; acc[i][j] = z; }

  for (int kk = 0; kk < 256; kk += 64) {
    __syncthreads();
    // stage 128x64 A and B: chunk q = c*256 + w*64 + lane; row=q>>3, cc=q&7
    // LDS linear; global source col-chunk pre-swizzled: cc ^ (row&7)
    #pragma unroll
    for (int c = 0; c < 4; ++c) {
      int q = c * 256 + w * 64 + lane;
      int row = q >> 3, cc = q & 7;
      int scol = ((cc ^ (row & 7)) * 8);
      GLDS16(aTile + (size_t)row * 256 + kk + scol, &As[(c * 256 + w * 64) * 8]);
      GLDS16(bTile + (size_t)row * 256 + kk + scol, &Bs[(c * 256 + w * 64) * 8]);
    }
    asm volatile("s_waitcnt vmcnt(0)");
    __syncthreads();
    #pragma unroll
    for (int ks2 = 0; ks2 < 2; ++ks2) {
      s16x8 af[4], bf[4];
      #pragma unroll
      for (int i = 0; i < 4; ++i)
        af[i] = *(const s16x8*)&As[(wr * 64 + i * 16 + fr) * 64 + (((ks2 * 4 + fq) ^ sx) * 8)];
      #pragma unroll
      for (int j = 0; j < 4; ++j)
        bf[j] = *(const s16x8*)&Bs[(wc * 64 + j * 16 + fr) * 64 + (((ks2 * 4 + fq) ^ sx) * 8)];
      #pragma unroll
      for (int i = 0; i < 4; ++i)
        #pragma unroll
        for (int j = 0; j < 4; ++j)
          acc[i][j] = __builtin_amdgcn_mfma_f32_16x16x32_bf16(af[i], bf[j], acc[i][j], 0, 0, 0);
    }
  }

  if (cb < 2) {
    #pragma unroll
    for (int i = 0; i < 4; ++i)
      #pragma unroll
      for (int j = 0; j < 4; ++j)
        #pragma unroll
        for (int r = 0; r < 4; ++r)
          kbuf[(size_t)(brow + wr * 64 + i * 16 + fq * 4 + r) * 256 + bcol + wc * 64 + j * 16 + fr]
              = f2bf(acc[i][j][r]);
  } else {
    size_t base = (size_t)((brow + wr * 64) >> 6) * 16384;
    #pragma unroll
    for (int i = 0; i < 4; ++i)
      #pragma unroll
      for (int j = 0; j < 4; ++j)
        #pragma unroll
        for (int r = 0; r < 4; ++r)
          vtbuf[base + (size_t)(bcol - 256 + wc * 64 + j * 16 + fr) * 64 + i * 16 + fq * 4 + r]
              = f2bf(acc[i][j][r]);
  }
}

// ---------------- slot LN + q projection ----------------
__global__ __launch_bounds__(256) void qproj_kernel(const float* __restrict__ slots, const float* __restrict__ Wq,
    const float* __restrict__ g, const float* __restrict__ be, float* __restrict__ gq)
{
  __shared__ __align__(16) float sl[8][256];
  int b = blockIdx.x, t = threadIdx.x;
  int lane = t & 63, w = t >> 6;
  #pragma unroll
  for (int s2 = 0; s2 < 2; ++s2) {
    int s = w * 2 + s2;
    f32x4 v = *(const f32x4*)&slots[(size_t)(b * 8 + s) * 256 + lane * 4];
    float s1 = v.x + v.y + v.z + v.w;
    float q1 = v.x*v.x + v.y*v.y + v.z*v.z + v.w*v.w;
    #pragma unroll
    for (int m = 1; m < 64; m <<= 1) { s1 += __shfl_xor(s1, m, 64); q1 += __shfl_xor(q1, m, 64); }
    float mu = s1 * (1.f / 256.f);
    float var = q1 * (1.f / 256.f) - mu * mu;
    float rstd = rsqrtf(var + 1e-3f);
    f32x4 gv = *(const f32x4*)&g[lane * 4];
    f32x4 bv = *(const f32x4*)&be[lane * 4];
    f32x4 o;
    o.x = (v.x - mu) * rstd * gv.x + bv.x;
    o.y = (v.y - mu) * rstd * gv.y + bv.y;
    o.z = (v.z - mu) * rstd * gv.z + bv.z;
    o.w = (v.w - mu) * rstd * gv.w + bv.w;
    *(f32x4*)&sl[s][lane * 4] = o;
  }
  __syncthreads();
  float a[8];
  #pragma unroll
  for (int s = 0; s < 8; ++s) a[s] = 0.f;
  const f32x4* wr = (const f32x4*)&Wq[(size_t)t * 256];
  for (int k = 0; k < 64; ++k) {
    f32x4 w4 = wr[k];
    #pragma unroll
    for (int s = 0; s < 8; ++s) a[s] += dot4(w4, *(const f32x4*)&sl[s][k * 4]);
  }
  #pragma unroll
  for (int s = 0; s < 8; ++s) gq[(size_t)(b * 8 + s) * 256 + t] = a[s] * 0.0625f;
}

// ---------------- MFMA attention: GLDS16 staging, swizzled tiles ----------------
// grid (CH, 64), block 256 (4 waves); 4096/CH n-rows per block in tiles of 64.
__global__ __launch_bounds__(256) void attn_kernel(
    const u16* __restrict__ kbuf, const u16* __restrict__ vtbuf,
    const float* __restrict__ gq, float* __restrict__ gUp, float* __restrict__ gdp)
{
  __shared__ __align__(16) u16 tb[64 * 256];      // k-tile [64][256] / vt-tile [256][64] / q fp32
  __shared__ __align__(16) u16 P[16 * 72];
  __shared__ float wden[4][8];
  const int b = blockIdx.y, chunk = blockIdx.x;
  const int t = threadIdx.x;
  const int lane = t & 63, w = t >> 6;
  const int fr = lane & 15, fq = lane >> 4;
  const int sx = fr & 7;
  const bool valid = fr < 8;

  {
    float* qs = (float*)tb;
    #pragma unroll
    for (int p = 0; p < 8; ++p) qs[t + p * 256] = gq[(size_t)b * 2048 + t + p * 256];
    u32* p32 = (u32*)P;
    p32[288 + t] = 0; if (t < 32) p32[544 + t] = 0;
  }
  __syncthreads();

  s16x8 qf[8];
  {
    const float* qs = (const float*)tb;
    if (valid) {
      #pragma unroll
      for (int ks = 0; ks < 8; ++ks) {
        f32x4 a = *(const f32x4*)&qs[fr * 256 + ks * 32 + fq * 8];
        f32x4 c = *(const f32x4*)&qs[fr * 256 + ks * 32 + fq * 8 + 4];
        s16x8 q8;
        q8[0] = (short)f2bf(a.x); q8[1] = (short)f2bf(a.y);
        q8[2] = (short)f2bf(a.z); q8[3] = (short)f2bf(a.w);
        q8[4] = (short)f2bf(c.x); q8[5] = (short)f2bf(c.y);
        q8[6] = (short)f2bf(c.z); q8[7] = (short)f2bf(c.w);
        qf[ks] = q8;
      }
    } else {
      #pragma unroll
      for (int ks = 0; ks < 8; ++ks) { s16x8 z = {0,0,0,0,0,0,0,0}; qf[ks] = z; }
    }
  }

  f32x4 uacc[4];
  #pragma unroll
  for (int ct = 0; ct < 4; ++ct) { f32x4 z = {0.f,0.f,0.f,0.f}; uacc[ct] = z; }
  float denom_loc = 0.f;

  for (int ti = 0; ti < GN / CH / 64; ++ti) {
    const int n0 = chunk * (GN / CH) + ti * 64;
    __syncthreads();                                   // prev tile consumed / q done
    // stage k-tile [64][256] linear via GLDS16; source chunk pre-swizzled
    {
      const u16* kg = &kbuf[((size_t)b * 4096 + n0) * 256];
      #pragma unroll
      for (int c = 0; c < 8; ++c) {
        int q = c * 256 + w * 64 + lane;
        int row = q >> 5, cc = q & 31;
        GLDS16(kg + (size_t)row * 256 + ((cc ^ (row & 7)) * 8), &tb[(c * 256 + w * 64) * 8]);
      }
    }
    asm volatile("s_waitcnt vmcnt(0)");
    __syncthreads();
    // dots: wave w -> n-rows w*16..+15
    f32x4 dacc = {0.f, 0.f, 0.f, 0.f};
    #pragma unroll
    for (int ks = 0; ks < 8; ++ks) {
      s16x8 a = *(const s16x8*)&tb[(w * 16 + fr) * 256 + (((ks * 4 + fq) ^ sx) * 8)];
      dacc = __builtin_amdgcn_mfma_f32_16x16x32_bf16(a, qf[ks], dacc, 0, 0, 0);
    }
    float pw[4];
    #pragma unroll
    for (int r = 0; r < 4; ++r) {
      float d = dacc[r];
      float m = d;
      #pragma unroll
      for (int msk = 1; msk < 8; msk <<= 1) m = fmaxf(m, __shfl_xor(m, msk, 64));
      float e = expf(d - m);
      float sm = e;
      #pragma unroll
      for (int msk = 1; msk < 8; msk <<= 1) sm += __shfl_xor(sm, msk, 64);
      pw[r] = e / sm + 1e-8f;
    }
    if (valid) {
      denom_loc += pw[0] + pw[1] + pw[2] + pw[3];
      u32 lo = (u32)f2bf(pw[0]) | ((u32)f2bf(pw[1]) << 16);
      u32 hi = (u32)f2bf(pw[2]) | ((u32)f2bf(pw[3]) << 16);
      *(u32*)&P[fr * 72 + w * 16 + fq * 4] = lo;
      *(u32*)&P[fr * 72 + w * 16 + fq * 4 + 2] = hi;
    }
    __syncthreads();                                   // k reads done, P visible
    // stage vt-tile [256][64] linear via GLDS16, pre-swizzled source
    {
      const u16* vg = &vtbuf[(size_t)(b * 64 + (n0 >> 6)) * 16384];
      #pragma unroll
      for (int c = 0; c < 8; ++c) {
        int q = c * 256 + w * 64 + lane;
        int row = q >> 3, cc = q & 7;
        GLDS16(vg + (size_t)row * 64 + ((cc ^ (row & 7)) * 8), &tb[(c * 256 + w * 64) * 8]);
      }
    }
    asm volatile("s_waitcnt vmcnt(0)");
    __syncthreads();
    {
      s16x8 pa0 = *(const s16x8*)&P[fr * 72 + fq * 8];
      s16x8 pa1 = *(const s16x8*)&P[fr * 72 + 32 + fq * 8];
      #pragma unroll
      for (int ct = 0; ct < 4; ++ct) {
        int row = w * 64 + ct * 16 + fr;
        s16x8 vb0 = *(const s16x8*)&tb[row * 64 + ((fq ^ sx) * 8)];
        s16x8 vb1 = *(const s16x8*)&tb[row * 64 + (((4 + fq) ^ sx) * 8)];
        uacc[ct] = __builtin_amdgcn_mfma_f32_16x16x32_bf16(pa0, vb0, uacc[ct], 0, 0, 0);
        uacc[ct] = __builtin_amdgcn_mfma_f32_16x16x32_bf16(pa1, vb1, uacc[ct], 0, 0, 0);
      }
    }
  }

  float dl = denom_loc;
  dl += __shfl_xor(dl, 16, 64);
  dl += __shfl_xor(dl, 32, 64);
  if (lane < 8) wden[w][lane] = dl;
  __syncthreads();
  if (t < 8) gdp[(chunk * 64 + b) * 8 + t] = wden[0][t] + wden[1][t] + wden[2][t] + wden[3][t];

  if (lane < 32) {
    size_t obase = (size_t)(chunk * 64 + b) * 8 * 256;
    #pragma unroll
    for (int ct = 0; ct < 4; ++ct)
      #pragma unroll
      for (int r = 0; r < 4; ++r)
        gUp[obase + (size_t)(fq * 4 + r) * 256 + w * 64 + ct * 16 + fr] = uacc[ct][r];
  }
}

// ---------------- update: GRU + LN + MLP via M=16 MFMA GEMMs, one block per batch ----------------
__global__ __launch_bounds__(256) void update_kernel(
    const float* __restrict__ gUp, const float* __restrict__ gdp,
    float* __restrict__ slots,
    const u16* __restrict__ Wcat, const float* __restrict__ b_ih, const float* __restrict__ b_hh,
    const u16* __restrict__ W1b, const float* __restrict__ b1,
    const u16* __restrict__ W2b, const float* __restrict__ b2,
    const float* __restrict__ lng, const float* __restrict__ lnb,
    float* __restrict__ out, int last)
{
  __shared__ __align__(16) u16 bufA[16 * 520];   // phase1 A=[u|s]; reused as h1 A2 for MLP2
  __shared__ __align__(16) u16 bufP[16 * 264];   // LN'd slots (MLP1 A)
  __shared__ float g[1024 * 10];                 // gate pre-activations [j][slot]
  __shared__ float nl[8 * 256];                  // news (GRU output, f32)
  __shared__ float sp[8 * 256];                  // prev slots
  __shared__ float scr[16];
  const int b = blockIdx.x;
  const int t = threadIdx.x;
  const int lane = t & 63, w = t >> 6;
  const int fr = lane & 15, fq = lane >> 4;

  // ---- phase 0: u = sum(partials)/denom; A = [u|s] bf16 ----
  #pragma unroll
  for (int s = 0; s < 8; ++s) {
    float den = 0.f, ua = 0.f;
    #pragma unroll 4
    for (int c = 0; c < CH; ++c) {
      den += gdp[(c * 64 + b) * 8 + s];
      ua  += gUp[((size_t)(c * 64 + b) * 8 + s) * 256 + t];
    }
    float u = ua / den;
    float spv = slots[(b * 8 + s) * 256 + t];
    bufA[s * 520 + t] = f2bf(u);
    bufA[s * 520 + 256 + t] = f2bf(spv);
    sp[s * 256 + t] = spv;
  }
  for (int i = t; i < 8 * 520; i += 256) bufA[8 * 520 + i] = 0;
  __syncthreads();

  // ---- phase 1: gates GEMM M=16, N=1024, K=512; wave w -> n in [w*256, w*256+256) ----
  {
    s16x8 afr[16];
    #pragma unroll
    for (int ks = 0; ks < 16; ++ks)
      afr[ks] = *(const s16x8*)&bufA[fr * 520 + ks * 32 + fq * 8];
    for (int nf = 0; nf < 16; ++nf) {
      int n0 = w * 256 + nf * 16;
      f32x4 acc = {0.f, 0.f, 0.f, 0.f};
      #pragma unroll
      for (int ks = 0; ks < 16; ++ks) {
        s16x8 bb = *(const s16x8*)&Wcat[(size_t)(n0 + fr) * 512 + ks * 32 + fq * 8];
        acc = __builtin_amdgcn_mfma_f32_16x16x32_bf16(afr[ks], bb, acc, 0, 0, 0);
      }
      if (fq < 2) {
        int j = n0 + fr;
        #pragma unroll
        for (int r = 0; r < 4; ++r) g[j * 10 + fq * 4 + r] = acc[r];
      }
    }
  }
  __syncthreads();

  // ---- phase 2: GRU elementwise; news -> nl ----
  {
    float bi0 = b_ih[t],       bh0 = b_hh[t];
    float bi1 = b_ih[256 + t], bh1 = b_hh[256 + t];
    float bi2 = b_ih[512 + t], bh2 = b_hh[512 + t];
    #pragma unroll
    for (int s = 0; s < 8; ++s) {
      float rr = 1.f / (1.f + expf(-(g[t * 10 + s] + bi0 + bh0)));
      float z  = 1.f / (1.f + expf(-(g[(256 + t) * 10 + s] + bi1 + bh1)));
      float xn = g[(512 + t) * 10 + s] + bi2;
      float hn = g[(768 + t) * 10 + s] + bh2;
      float nn = tanhf(xn + rr * hn);
      nl[s * 256 + t] = (1.f - z) * nn + z * sp[s * 256 + t];
    }
  }
  __syncthreads();

  // ---- LN over d per slot: wave w handles slots 2w, 2w+1 ----
  {
    int ln_ = t & 63;
    #pragma unroll
    for (int j = 0; j < 2; ++j) {
      int sl = w * 2 + j;
      f32x4 v = *(const f32x4*)&nl[sl * 256 + ln_ * 4];
      float s1 = v.x + v.y + v.z + v.w;
      float s2 = v.x*v.x + v.y*v.y + v.z*v.z + v.w*v.w;
      #pragma unroll
      for (int m = 1; m < 64; m <<= 1) { s1 += __shfl_xor(s1, m, 64); s2 += __shfl_xor(s2, m, 64); }
      if (ln_ == 0) {
        float mu = s1 * (1.f / 256.f);
        float var = s2 * (1.f / 256.f) - mu * mu;
        scr[sl * 2] = mu;
        scr[sl * 2 + 1] = rsqrtf(var + 1e-3f);
      }
    }
  }
  __syncthreads();
  {
    float lg = lng[t], lb = lnb[t];
    #pragma unroll
    for (int s = 0; s < 8; ++s)
      bufP[s * 264 + t] = f2bf((nl[s * 256 + t] - scr[s * 2]) * scr[s * 2 + 1] * lg + lb);
    for (int i = t; i < 8 * 264; i += 256) bufP[8 * 264 + i] = 0;
  }
  __syncthreads();

  // ---- phase 3: MLP1 GEMM M=16, N=512, K=256; relu -> bufA (h1, bf16) ----
  {
    s16x8 pa[8];
    #pragma unroll
    for (int ks = 0; ks < 8; ++ks)
      pa[ks] = *(const s16x8*)&bufP[fr * 264 + ks * 32 + fq * 8];
    for (int nf = 0; nf < 8; ++nf) {
      int n0 = w * 128 + nf * 16;
      f32x4 acc = {0.f, 0.f, 0.f, 0.f};
      #pragma unroll
      for (int ks = 0; ks < 8; ++ks) {
        s16x8 bb = *(const s16x8*)&W1b[(size_t)(n0 + fr) * 256 + ks * 32 + fq * 8];
        acc = __builtin_amdgcn_mfma_f32_16x16x32_bf16(pa[ks], bb, acc, 0, 0, 0);
      }
      if (fq < 2) {
        float bb1 = b1[n0 + fr];
        #pragma unroll
        for (int r = 0; r < 4; ++r)
          bufA[(fq * 4 + r) * 520 + n0 + fr] = f2bf(fmaxf(acc[r] + bb1, 0.f));
      }
    }
  }
  __syncthreads();

  // ---- phase 4: MLP2 GEMM M=16, N=256, K=512; + residual + out ----
  {
    s16x8 ha[16];
    #pragma unroll
    for (int ks = 0; ks < 16; ++ks)
      ha[ks] = *(const s16x8*)&bufA[fr * 520 + ks * 32 + fq * 8];
    for (int nf = 0; nf < 4; ++nf) {
      int n0 = w * 64 + nf * 16;
      f32x4 acc = {0.f, 0.f, 0.f, 0.f};
      #pragma unroll
      for (int ks = 0; ks < 16; ++ks) {
        s16x8 bb = *(const s16x8*)&W2b[(size_t)(n0 + fr) * 512 + ks * 32 + fq * 8];
        acc = __builtin_amdgcn_mfma_f32_16x16x32_bf16(ha[ks], bb, acc, 0, 0, 0);
      }
      if (fq < 2) {
        int d = n0 + fr;
        float bb2 = b2[d];
        #pragma unroll
        for (int r = 0; r < 4; ++r) {
          int sl = fq * 4 + r;
          float val = acc[r] + nl[sl * 256 + d] + bb2;
          slots[(b * 8 + sl) * 256 + d] = val;
          if (last) out[(b * 8 + sl) * 256 + d] = val;
        }
      }
    }
  }
}

extern "C" void kernel_launch(void* const* d_in, const int* in_sizes, int n_in,
                              void* d_out, int out_size, void* d_ws, size_t ws_size,
                              hipStream_t stream) {
  const float* inputs   = (const float*)d_in[0];
  const float* noise    = (const float*)d_in[1];
  const float* slots_mu = (const float*)d_in[2];
  const float* slots_ls = (const float*)d_in[3];
  const float* Wq   = (const float*)d_in[4];
  const float* Wk   = (const float*)d_in[5];
  const float* Wv   = (const float*)d_in[6];
  const float* W_ih = (const float*)d_in[7];
  const float* W_hh = (const float*)d_in[8];
  const float* b_ih = (const float*)d_in[9];
  const float* b_hh = (const float*)d_in[10];
  const float* W1   = (const float*)d_in[11];
  const float* b1   = (const float*)d_in[12];
  const float* W2   = (const float*)d_in[13];
  const float* b2   = (const float*)d_in[14];
  const float* ln_in_g = (const float*)d_in[15];
  const float* ln_in_b = (const float*)d_in[16];
  const float* ln_s_g  = (const float*)d_in[17];
  const float* ln_s_b  = (const float*)d_in[18];
  const float* ln_ff_g = (const float*)d_in[19];
  const float* ln_ff_b = (const float*)d_in[20];
  float* out = (float*)d_out;

  char* w = (char*)d_ws;
  // region0: xbuf (ln_bf16 -> gemm) overlays gUp/gdp (attn -> update)
  u16* xbuf = (u16*)w;
  float* gUp = (float*)w;
  float* gdp = (float*)(w + (size_t)CH * 64 * 8 * 256 * 4);
  w += (size_t)GM * 256 * 2;                                  // 128 MB
  u16* kbuf = (u16*)w;     w += (size_t)GM * 256 * 2;         // 128 MB
  u16* vtbuf = (u16*)w;    w += (size_t)GM * 256 * 2;         // 128 MB
  u16* wkv = (u16*)w;      w += (size_t)512 * 256 * 2;        // 256 KB
  u16* Wcat = (u16*)w;     w += (size_t)1024 * 512 * 2;       // 1 MB
  u16* W1b = (u16*)w;      w += (size_t)512 * 256 * 2;        // 256 KB
  u16* W2b = (u16*)w;      w += (size_t)256 * 512 * 2;        // 256 KB
  float* slots = (float*)w; w += (size_t)131072 * 4;
  float* gq = (float*)w;    w += (size_t)131072 * 4;

  init_slots_kernel<<<512, 256, 0, stream>>>(noise, slots_mu, slots_ls, slots);
  wprep_kernel<<<3584, 256, 0, stream>>>(Wk, Wv, W_ih, W_hh, W1, W2, wkv, Wcat, W1b, W2b);
  ln_bf16_kernel<<<GM / 4, 256, 0, stream>>>(inputs, ln_in_g, ln_in_b, xbuf);
  gemm_kv<<<dim3(GM / 128, 4), 256, 0, stream>>>(xbuf, wkv, kbuf, vtbuf);

  for (int it = 0; it < 3; ++it) {
    qproj_kernel<<<64, 256, 0, stream>>>(slots, Wq, ln_s_g, ln_s_b, gq);
    attn_kernel<<<dim3(CH, 64), 256, 0, stream>>>(kbuf, vtbuf, gq, gUp, gdp);
    update_kernel<<<64, 256, 0, stream>>>(gUp, gdp, slots, Wcat, b_ih, b_hh,
                                          W1b, b1, W2b, b2, ln_ff_g, ln_ff_b, out, it == 2);
  }
}

// Round 6
// 746.959 us; speedup vs baseline: 1.2353x; 1.0391x over previous
//
#include <hip/hip_runtime.h>

typedef unsigned short u16;
typedef unsigned int u32;
typedef __attribute__((ext_vector_type(4))) float f32x4;
typedef __attribute__((ext_vector_type(8))) short s16x8;

#define GM 262144   // B*N rows
#define GB 64
#define GN 4096
#define GC 256
#define GD 256
#define GS 8
#define GH 512
#define CH 32       // attn chunks per batch

#define GLDS16(G, L) __builtin_amdgcn_global_load_lds( \
    (const __attribute__((address_space(1))) void*)(G), \
    (__attribute__((address_space(3))) void*)(L), 16, 0, 0)

__device__ __forceinline__ float bf2f(u16 u) {
  union { unsigned int i; float f; } c; c.i = ((unsigned int)u) << 16; return c.f;
}
__device__ __forceinline__ u16 f2bf(float f) {
  union { float f; unsigned int i; } c; c.f = f;
  unsigned int x = c.i;
  unsigned int r = x + 0x7FFFu + ((x >> 16) & 1u);
  return (u16)(r >> 16);
}
__device__ __forceinline__ float dot4(f32x4 a, f32x4 b) {
  return a.x*b.x + a.y*b.y + a.z*b.z + a.w*b.w;
}

// ---------------- slots init ----------------
__global__ void init_slots_kernel(const float* __restrict__ noise, const float* __restrict__ smu,
                                  const float* __restrict__ sls, float* __restrict__ slots)
{
  int i = blockIdx.x * 256 + threadIdx.x;
  int d = i & 255;
  slots[i] = smu[d] + expf(sls[d]) * noise[i];
}

// ---------------- weight prep: wkv, Wcat, W1b, W2b, Wqb (bf16) ----------------
// Wcat rows: [0,512) = [Wih_r,z | Whh_r,z]; [512,768) = [Wih_n | 0]; [768,1024) = [0 | Whh_n]
__global__ void wprep_kernel(const float* __restrict__ Wk, const float* __restrict__ Wv,
                             const float* __restrict__ Wih, const float* __restrict__ Whh,
                             const float* __restrict__ W1, const float* __restrict__ W2,
                             const float* __restrict__ Wq,
                             u16* __restrict__ wkv, u16* __restrict__ Wcat,
                             u16* __restrict__ W1b, u16* __restrict__ W2b,
                             u16* __restrict__ Wqb)
{
  int i = blockIdx.x * 256 + threadIdx.x;       // 983040 total
  if (i < 131072) {
    wkv[i] = f2bf(i < 65536 ? Wk[i] : Wv[i - 65536]);
  } else if (i < 655360) {
    int j2 = i - 131072;
    int r = j2 >> 9, k = j2 & 511;
    float v;
    if (r < 512)      v = (k < 256) ? Wih[r * 256 + k] : Whh[r * 256 + (k - 256)];
    else if (r < 768) v = (k < 256) ? Wih[r * 256 + k] : 0.f;
    else              v = (k < 256) ? 0.f : Whh[(r - 256) * 256 + (k - 256)];
    Wcat[j2] = f2bf(v);
  } else if (i < 786432) {
    W1b[i - 655360] = f2bf(W1[i - 655360]);
  } else if (i < 917504) {
    W2b[i - 786432] = f2bf(W2[i - 786432]);
  } else {
    Wqb[i - 917504] = f2bf(Wq[i - 917504]);
  }
}

// ---------------- LN(inputs) -> bf16 xbuf ----------------
__global__ __launch_bounds__(256) void ln_bf16_kernel(
    const float* __restrict__ x, const float* __restrict__ g, const float* __restrict__ be,
    u16* __restrict__ xbuf)
{
  int row = blockIdx.x * 4 + (threadIdx.x >> 6);
  int lane = threadIdx.x & 63;
  f32x4 v = *(const f32x4*)&x[(size_t)row * 256 + lane * 4];
  float s = v.x + v.y + v.z + v.w;
  float sq = v.x*v.x + v.y*v.y + v.z*v.z + v.w*v.w;
  #pragma unroll
  for (int m = 1; m < 64; m <<= 1) { s += __shfl_xor(s, m, 64); sq += __shfl_xor(sq, m, 64); }
  float mu = s * (1.f / 256.f);
  float var = sq * (1.f / 256.f) - mu * mu;
  float rstd = rsqrtf(var + 1e-3f);
  f32x4 gv = *(const f32x4*)&g[lane * 4];
  f32x4 bv = *(const f32x4*)&be[lane * 4];
  uint2 pk;
  pk.x = (u32)f2bf((v.x - mu) * rstd * gv.x + bv.x)
       | ((u32)f2bf((v.y - mu) * rstd * gv.y + bv.y) << 16);
  pk.y = (u32)f2bf((v.z - mu) * rstd * gv.z + bv.z)
       | ((u32)f2bf((v.w - mu) * rstd * gv.w + bv.w) << 16);
  *(uint2*)&xbuf[(size_t)row * 256 + lane * 4] = pk;
}

// ---------------- K/V projection GEMM: 128x256 tile, 8 waves, BK=64, swizzled GLDS16 ----------
// grid (2048, 2): cb=0 -> K (kbuf row-major), cb=1 -> V (vtbuf transposed tiles).
__global__ __launch_bounds__(512) void gemm_kv(
    const u16* __restrict__ xbuf, const u16* __restrict__ wkv,
    u16* __restrict__ kbuf, u16* __restrict__ vtbuf)
{
  __shared__ __align__(16) u16 As[128 * 64];   // 16 KB
  __shared__ __align__(16) u16 Bs[256 * 64];   // 32 KB
  const int t = threadIdx.x;
  const int brow = blockIdx.x * 128;
  const int cb = blockIdx.y;
  const int lane = t & 63, w = t >> 6;
  const int wr = w >> 2, wc = w & 3;           // wave grid 2 x 4 (64x64 each)
  const int fr = lane & 15, fq = lane >> 4;
  const int sx = fr & 7;

  const u16* aTile = xbuf + (size_t)brow * 256;
  const u16* bTile = wkv + (size_t)(cb << 8) * 256;

  f32x4 acc[4][4];
  #pragma unroll
  for (int i = 0; i < 4; ++i)
    #pragma unroll
    for (int j = 0; j < 4; ++j) { f32x4 z = {0.f,0.f,0.f,0.f}; acc[i][j] = z; }

  for (int kk = 0; kk < 256; kk += 64) {
    __syncthreads();
    // stage A 128x64 (1024 chunks), B 256x64 (2048 chunks); source chunk pre-swizzled
    #pragma unroll
    for (int c = 0; c < 2; ++c) {
      int q = c * 512 + t;
      int row = q >> 3, cc = q & 7;
      GLDS16(aTile + (size_t)row * 256 + kk + ((cc ^ (row & 7)) * 8), &As[q * 8]);
    }
    #pragma unroll
    for (int c = 0; c < 4; ++c) {
      int q = c * 512 + t;
      int row = q >> 3, cc = q & 7;
      GLDS16(bTile + (size_t)row * 256 + kk + ((cc ^ (row & 7)) * 8), &Bs[q * 8]);
    }
    asm volatile("s_waitcnt vmcnt(0)");
    __syncthreads();
    #pragma unroll
    for (int ks2 = 0; ks2 < 2; ++ks2) {
      s16x8 af[4], bf[4];
      #pragma unroll
      for (int i = 0; i < 4; ++i)
        af[i] = *(const s16x8*)&As[(wr * 64 + i * 16 + fr) * 64 + (((ks2 * 4 + fq) ^ sx) * 8)];
      #pragma unroll
      for (int j = 0; j < 4; ++j)
        bf[j] = *(const s16x8*)&Bs[(wc * 64 + j * 16 + fr) * 64 + (((ks2 * 4 + fq) ^ sx) * 8)];
      #pragma unroll
      for (int i = 0; i < 4; ++i)
        #pragma unroll
        for (int j = 0; j < 4; ++j)
          acc[i][j] = __builtin_amdgcn_mfma_f32_16x16x32_bf16(af[i], bf[j], acc[i][j], 0, 0, 0);
    }
  }

  if (cb == 0) {
    #pragma unroll
    for (int i = 0; i < 4; ++i)
      #pragma unroll
      for (int j = 0; j < 4; ++j)
        #pragma unroll
        for (int r = 0; r < 4; ++r)
          kbuf[(size_t)(brow + wr * 64 + i * 16 + fq * 4 + r) * 256 + wc * 64 + j * 16 + fr]
              = f2bf(acc[i][j][r]);
  } else {
    // V transposed tiles: vtbuf[ntile][d][64]; this wave's 64 rows = one n-tile
    size_t base = (size_t)((brow >> 6) + wr) * 16384;
    #pragma unroll
    for (int i = 0; i < 4; ++i)
      #pragma unroll
      for (int j = 0; j < 4; ++j)
        #pragma unroll
        for (int r = 0; r < 4; ++r)
          vtbuf[base + (size_t)(wc * 64 + j * 16 + fr) * 64 + i * 16 + fq * 4 + r]
              = f2bf(acc[i][j][r]);
  }
}

// ---------------- slot LN + q projection (iter 0 only) ----------------
__global__ __launch_bounds__(256) void qproj_kernel(const float* __restrict__ slots, const float* __restrict__ Wq,
    const float* __restrict__ g, const float* __restrict__ be, float* __restrict__ gq)
{
  __shared__ __align__(16) float sl[8][256];
  int b = blockIdx.x, t = threadIdx.x;
  int lane = t & 63, w = t >> 6;
  #pragma unroll
  for (int s2 = 0; s2 < 2; ++s2) {
    int s = w * 2 + s2;
    f32x4 v = *(const f32x4*)&slots[(size_t)(b * 8 + s) * 256 + lane * 4];
    float s1 = v.x + v.y + v.z + v.w;
    float q1 = v.x*v.x + v.y*v.y + v.z*v.z + v.w*v.w;
    #pragma unroll
    for (int m = 1; m < 64; m <<= 1) { s1 += __shfl_xor(s1, m, 64); q1 += __shfl_xor(q1, m, 64); }
    float mu = s1 * (1.f / 256.f);
    float var = q1 * (1.f / 256.f) - mu * mu;
    float rstd = rsqrtf(var + 1e-3f);
    f32x4 gv = *(const f32x4*)&g[lane * 4];
    f32x4 bv = *(const f32x4*)&be[lane * 4];
    f32x4 o;
    o.x = (v.x - mu) * rstd * gv.x + bv.x;
    o.y = (v.y - mu) * rstd * gv.y + bv.y;
    o.z = (v.z - mu) * rstd * gv.z + bv.z;
    o.w = (v.w - mu) * rstd * gv.w + bv.w;
    *(f32x4*)&sl[s][lane * 4] = o;
  }
  __syncthreads();
  float a[8];
  #pragma unroll
  for (int s = 0; s < 8; ++s) a[s] = 0.f;
  const f32x4* wr = (const f32x4*)&Wq[(size_t)t * 256];
  for (int k = 0; k < 64; ++k) {
    f32x4 w4 = wr[k];
    #pragma unroll
    for (int s = 0; s < 8; ++s) a[s] += dot4(w4, *(const f32x4*)&sl[s][k * 4]);
  }
  #pragma unroll
  for (int s = 0; s < 8; ++s) gq[(size_t)(b * 8 + s) * 256 + t] = a[s] * 0.0625f;
}

// ---------------- MFMA attention: GLDS16 staging, swizzled tiles ----------------
// grid (CH, 64), block 256 (4 waves); 4096/CH n-rows per block in tiles of 64.
__global__ __launch_bounds__(256) void attn_kernel(
    const u16* __restrict__ kbuf, const u16* __restrict__ vtbuf,
    const float* __restrict__ gq, float* __restrict__ gUp, float* __restrict__ gdp)
{
  __shared__ __align__(16) u16 tb[64 * 256];      // k-tile [64][256] / vt-tile [256][64] / q fp32
  __shared__ __align__(16) u16 P[16 * 72];
  __shared__ float wden[4][8];
  const int b = blockIdx.y, chunk = blockIdx.x;
  const int t = threadIdx.x;
  const int lane = t & 63, w = t >> 6;
  const int fr = lane & 15, fq = lane >> 4;
  const int sx = fr & 7;
  const bool valid = fr < 8;

  {
    float* qs = (float*)tb;
    #pragma unroll
    for (int p = 0; p < 8; ++p) qs[t + p * 256] = gq[(size_t)b * 2048 + t + p * 256];
    u32* p32 = (u32*)P;
    p32[288 + t] = 0; if (t < 32) p32[544 + t] = 0;
  }
  __syncthreads();

  s16x8 qf[8];
  {
    const float* qs = (const float*)tb;
    if (valid) {
      #pragma unroll
      for (int ks = 0; ks < 8; ++ks) {
        f32x4 a = *(const f32x4*)&qs[fr * 256 + ks * 32 + fq * 8];
        f32x4 c = *(const f32x4*)&qs[fr * 256 + ks * 32 + fq * 8 + 4];
        s16x8 q8;
        q8[0] = (short)f2bf(a.x); q8[1] = (short)f2bf(a.y);
        q8[2] = (short)f2bf(a.z); q8[3] = (short)f2bf(a.w);
        q8[4] = (short)f2bf(c.x); q8[5] = (short)f2bf(c.y);
        q8[6] = (short)f2bf(c.z); q8[7] = (short)f2bf(c.w);
        qf[ks] = q8;
      }
    } else {
      #pragma unroll
      for (int ks = 0; ks < 8; ++ks) { s16x8 z = {0,0,0,0,0,0,0,0}; qf[ks] = z; }
    }
  }

  f32x4 uacc[4];
  #pragma unroll
  for (int ct = 0; ct < 4; ++ct) { f32x4 z = {0.f,0.f,0.f,0.f}; uacc[ct] = z; }
  float denom_loc = 0.f;

  for (int ti = 0; ti < GN / CH / 64; ++ti) {
    const int n0 = chunk * (GN / CH) + ti * 64;
    __syncthreads();
    {
      const u16* kg = &kbuf[((size_t)b * 4096 + n0) * 256];
      #pragma unroll
      for (int c = 0; c < 8; ++c) {
        int q = c * 256 + w * 64 + lane;
        int row = q >> 5, cc = q & 31;
        GLDS16(kg + (size_t)row * 256 + ((cc ^ (row & 7)) * 8), &tb[(c * 256 + w * 64) * 8]);
      }
    }
    asm volatile("s_waitcnt vmcnt(0)");
    __syncthreads();
    f32x4 dacc = {0.f, 0.f, 0.f, 0.f};
    #pragma unroll
    for (int ks = 0; ks < 8; ++ks) {
      s16x8 a = *(const s16x8*)&tb[(w * 16 + fr) * 256 + (((ks * 4 + fq) ^ sx) * 8)];
      dacc = __builtin_amdgcn_mfma_f32_16x16x32_bf16(a, qf[ks], dacc, 0, 0, 0);
    }
    float pw[4];
    #pragma unroll
    for (int r = 0; r < 4; ++r) {
      float d = dacc[r];
      float m = d;
      #pragma unroll
      for (int msk = 1; msk < 8; msk <<= 1) m = fmaxf(m, __shfl_xor(m, msk, 64));
      float e = expf(d - m);
      float sm = e;
      #pragma unroll
      for (int msk = 1; msk < 8; msk <<= 1) sm += __shfl_xor(sm, msk, 64);
      pw[r] = e / sm + 1e-8f;
    }
    if (valid) {
      denom_loc += pw[0] + pw[1] + pw[2] + pw[3];
      u32 lo = (u32)f2bf(pw[0]) | ((u32)f2bf(pw[1]) << 16);
      u32 hi = (u32)f2bf(pw[2]) | ((u32)f2bf(pw[3]) << 16);
      *(u32*)&P[fr * 72 + w * 16 + fq * 4] = lo;
      *(u32*)&P[fr * 72 + w * 16 + fq * 4 + 2] = hi;
    }
    __syncthreads();
    {
      const u16* vg = &vtbuf[(size_t)(b * 64 + (n0 >> 6)) * 16384];
      #pragma unroll
      for (int c = 0; c < 8; ++c) {
        int q = c * 256 + w * 64 + lane;
        int row = q >> 3, cc = q & 7;
        GLDS16(vg + (size_t)row * 64 + ((cc ^ (row & 7)) * 8), &tb[(c * 256 + w * 64) * 8]);
      }
    }
    asm volatile("s_waitcnt vmcnt(0)");
    __syncthreads();
    {
      s16x8 pa0 = *(const s16x8*)&P[fr * 72 + fq * 8];
      s16x8 pa1 = *(const s16x8*)&P[fr * 72 + 32 + fq * 8];
      #pragma unroll
      for (int ct = 0; ct < 4; ++ct) {
        int row = w * 64 + ct * 16 + fr;
        s16x8 vb0 = *(const s16x8*)&tb[row * 64 + ((fq ^ sx) * 8)];
        s16x8 vb1 = *(const s16x8*)&tb[row * 64 + (((4 + fq) ^ sx) * 8)];
        uacc[ct] = __builtin_amdgcn_mfma_f32_16x16x32_bf16(pa0, vb0, uacc[ct], 0, 0, 0);
        uacc[ct] = __builtin_amdgcn_mfma_f32_16x16x32_bf16(pa1, vb1, uacc[ct], 0, 0, 0);
      }
    }
  }

  float dl = denom_loc;
  dl += __shfl_xor(dl, 16, 64);
  dl += __shfl_xor(dl, 32, 64);
  if (lane < 8) wden[w][lane] = dl;
  __syncthreads();
  if (t < 8) gdp[(chunk * 64 + b) * 8 + t] = wden[0][t] + wden[1][t] + wden[2][t] + wden[3][t];

  if (lane < 32) {
    size_t obase = (size_t)(chunk * 64 + b) * 8 * 256;
    #pragma unroll
    for (int ct = 0; ct < 4; ++ct)
      #pragma unroll
      for (int r = 0; r < 4; ++r)
        gUp[obase + (size_t)(fq * 4 + r) * 256 + w * 64 + ct * 16 + fr] = uacc[ct][r];
  }
}

// ---------------- update: GRU + LN + MLP (+ fused next-iter qproj), MFMA M=16 GEMMs ----------
__global__ __launch_bounds__(256) void update_kernel(
    const float* __restrict__ gUp, const float* __restrict__ gdp,
    float* __restrict__ slots,
    const u16* __restrict__ Wcat, const float* __restrict__ b_ih, const float* __restrict__ b_hh,
    const u16* __restrict__ W1b, const float* __restrict__ b1,
    const u16* __restrict__ W2b, const float* __restrict__ b2,
    const float* __restrict__ lng, const float* __restrict__ lnb,
    const u16* __restrict__ Wqb, const float* __restrict__ lnsg, const float* __restrict__ lnsb,
    float* __restrict__ gq, float* __restrict__ out, int last)
{
  __shared__ __align__(16) u16 bufA[16 * 520];
  __shared__ __align__(16) u16 bufP[16 * 264];
  __shared__ float g[1024 * 10];
  __shared__ float nl[8 * 256];
  __shared__ float sp[8 * 256];
  __shared__ float scr[16];
  const int b = blockIdx.x;
  const int t = threadIdx.x;
  const int lane = t & 63, w = t >> 6;
  const int fr = lane & 15, fq = lane >> 4;

  // ---- phase 0 ----
  #pragma unroll
  for (int s = 0; s < 8; ++s) {
    float den = 0.f, ua = 0.f;
    #pragma unroll 4
    for (int c = 0; c < CH; ++c) {
      den += gdp[(c * 64 + b) * 8 + s];
      ua  += gUp[((size_t)(c * 64 + b) * 8 + s) * 256 + t];
    }
    float u = ua / den;
    float spv = slots[(b * 8 + s) * 256 + t];
    bufA[s * 520 + t] = f2bf(u);
    bufA[s * 520 + 256 + t] = f2bf(spv);
    sp[s * 256 + t] = spv;
  }
  for (int i = t; i < 8 * 520; i += 256) bufA[8 * 520 + i] = 0;
  for (int i = t; i < 8 * 264; i += 256) bufP[8 * 264 + i] = 0;
  __syncthreads();

  // ---- phase 1: gates GEMM M=16 N=1024 K=512 ----
  {
    s16x8 afr[16];
    #pragma unroll
    for (int ks = 0; ks < 16; ++ks)
      afr[ks] = *(const s16x8*)&bufA[fr * 520 + ks * 32 + fq * 8];
    for (int nf = 0; nf < 16; ++nf) {
      int n0 = w * 256 + nf * 16;
      f32x4 acc = {0.f, 0.f, 0.f, 0.f};
      #pragma unroll
      for (int ks = 0; ks < 16; ++ks) {
        s16x8 bb = *(const s16x8*)&Wcat[(size_t)(n0 + fr) * 512 + ks * 32 + fq * 8];
        acc = __builtin_amdgcn_mfma_f32_16x16x32_bf16(afr[ks], bb, acc, 0, 0, 0);
      }
      if (fq < 2) {
        int j = n0 + fr;
        #pragma unroll
        for (int r = 0; r < 4; ++r) g[j * 10 + fq * 4 + r] = acc[r];
      }
    }
  }
  __syncthreads();

  // ---- phase 2: GRU elementwise ----
  {
    float bi0 = b_ih[t],       bh0 = b_hh[t];
    float bi1 = b_ih[256 + t], bh1 = b_hh[256 + t];
    float bi2 = b_ih[512 + t], bh2 = b_hh[512 + t];
    #pragma unroll
    for (int s = 0; s < 8; ++s) {
      float rr = 1.f / (1.f + expf(-(g[t * 10 + s] + bi0 + bh0)));
      float z  = 1.f / (1.f + expf(-(g[(256 + t) * 10 + s] + bi1 + bh1)));
      float xn = g[(512 + t) * 10 + s] + bi2;
      float hn = g[(768 + t) * 10 + s] + bh2;
      float nn = tanhf(xn + rr * hn);
      nl[s * 256 + t] = (1.f - z) * nn + z * sp[s * 256 + t];
    }
  }
  __syncthreads();

  // ---- LN_ff ----
  {
    int ln_ = t & 63;
    #pragma unroll
    for (int j = 0; j < 2; ++j) {
      int sl = w * 2 + j;
      f32x4 v = *(const f32x4*)&nl[sl * 256 + ln_ * 4];
      float s1 = v.x + v.y + v.z + v.w;
      float s2 = v.x*v.x + v.y*v.y + v.z*v.z + v.w*v.w;
      #pragma unroll
      for (int m = 1; m < 64; m <<= 1) { s1 += __shfl_xor(s1, m, 64); s2 += __shfl_xor(s2, m, 64); }
      if (ln_ == 0) {
        float mu = s1 * (1.f / 256.f);
        float var = s2 * (1.f / 256.f) - mu * mu;
        scr[sl * 2] = mu;
        scr[sl * 2 + 1] = rsqrtf(var + 1e-3f);
      }
    }
  }
  __syncthreads();
  {
    float lg = lng[t], lb = lnb[t];
    #pragma unroll
    for (int s = 0; s < 8; ++s)
      bufP[s * 264 + t] = f2bf((nl[s * 256 + t] - scr[s * 2]) * scr[s * 2 + 1] * lg + lb);
  }
  __syncthreads();

  // ---- phase 3: MLP1 M=16 N=512 K=256, relu ----
  {
    s16x8 pa[8];
    #pragma unroll
    for (int ks = 0; ks < 8; ++ks)
      pa[ks] = *(const s16x8*)&bufP[fr * 264 + ks * 32 + fq * 8];
    for (int nf = 0; nf < 8; ++nf) {
      int n0 = w * 128 + nf * 16;
      f32x4 acc = {0.f, 0.f, 0.f, 0.f};
      #pragma unroll
      for (int ks = 0; ks < 8; ++ks) {
        s16x8 bb = *(const s16x8*)&W1b[(size_t)(n0 + fr) * 256 + ks * 32 + fq * 8];
        acc = __builtin_amdgcn_mfma_f32_16x16x32_bf16(pa[ks], bb, acc, 0, 0, 0);
      }
      if (fq < 2) {
        float bb1 = b1[n0 + fr];
        #pragma unroll
        for (int r = 0; r < 4; ++r)
          bufA[(fq * 4 + r) * 520 + n0 + fr] = f2bf(fmaxf(acc[r] + bb1, 0.f));
      }
    }
  }
  __syncthreads();

  // ---- phase 4: MLP2 M=16 N=256 K=512, +residual; new slots -> sp ----
  {
    s16x8 ha[16];
    #pragma unroll
    for (int ks = 0; ks < 16; ++ks)
      ha[ks] = *(const s16x8*)&bufA[fr * 520 + ks * 32 + fq * 8];
    for (int nf = 0; nf < 4; ++nf) {
      int n0 = w * 64 + nf * 16;
      f32x4 acc = {0.f, 0.f, 0.f, 0.f};
      #pragma unroll
      for (int ks = 0; ks < 16; ++ks) {
        s16x8 bb = *(const s16x8*)&W2b[(size_t)(n0 + fr) * 512 + ks * 32 + fq * 8];
        acc = __builtin_amdgcn_mfma_f32_16x16x32_bf16(ha[ks], bb, acc, 0, 0, 0);
      }
      if (fq < 2) {
        int d = n0 + fr;
        float bb2 = b2[d];
        #pragma unroll
        for (int r = 0; r < 4; ++r) {
          int sl = fq * 4 + r;
          float val = acc[r] + nl[sl * 256 + d] + bb2;
          slots[(b * 8 + sl) * 256 + d] = val;
          sp[sl * 256 + d] = val;
          if (last) out[(b * 8 + sl) * 256 + d] = val;
        }
      }
    }
  }
  if (last) return;
  __syncthreads();

  // ---- fused next-iter qproj: LN_s(new slots) @ Wq^T * SCALE -> gq ----
  {
    int ln_ = t & 63;
    #pragma unroll
    for (int j = 0; j < 2; ++j) {
      int sl = w * 2 + j;
      f32x4 v = *(const f32x4*)&sp[sl * 256 + ln_ * 4];
      float s1 = v.x + v.y + v.z + v.w;
      float s2 = v.x*v.x + v.y*v.y + v.z*v.z + v.w*v.w;
      #pragma unroll
      for (int m = 1; m < 64; m <<= 1) { s1 += __shfl_xor(s1, m, 64); s2 += __shfl_xor(s2, m, 64); }
      if (ln_ == 0) {
        float mu = s1 * (1.f / 256.f);
        float var = s2 * (1.f / 256.f) - mu * mu;
        scr[sl * 2] = mu;
        scr[sl * 2 + 1] = rsqrtf(var + 1e-3f);
      }
    }
  }
  __syncthreads();
  {
    float lg = lnsg[t], lb = lnsb[t];
    #pragma unroll
    for (int s = 0; s < 8; ++s)
      bufP[s * 264 + t] = f2bf((sp[s * 256 + t] - scr[s * 2]) * scr[s * 2 + 1] * lg + lb);
  }
  __syncthreads();
  {
    s16x8 pa[8];
    #pragma unroll
    for (int ks = 0; ks < 8; ++ks)
      pa[ks] = *(const s16x8*)&bufP[fr * 264 + ks * 32 + fq * 8];
    for (int nf = 0; nf < 4; ++nf) {
      int n0 = w * 64 + nf * 16;
      f32x4 acc = {0.f, 0.f, 0.f, 0.f};
      #pragma unroll
      for (int ks = 0; ks < 8; ++ks) {
        s16x8 bb = *(const s16x8*)&Wqb[(size_t)(n0 + fr) * 256 + ks * 32 + fq * 8];
        acc = __builtin_amdgcn_mfma_f32_16x16x32_bf16(pa[ks], bb, acc, 0, 0, 0);
      }
      if (fq < 2) {
        int e = n0 + fr;
        #pragma unroll
        for (int r = 0; r < 4; ++r)
          gq[(size_t)(b * 8 + fq * 4 + r) * 256 + e] = acc[r] * 0.0625f;
      }
    }
  }
}

extern "C" void kernel_launch(void* const* d_in, const int* in_sizes, int n_in,
                              void* d_out, int out_size, void* d_ws, size_t ws_size,
                              hipStream_t stream) {
  const float* inputs   = (const float*)d_in[0];
  const float* noise    = (const float*)d_in[1];
  const float* slots_mu = (const float*)d_in[2];
  const float* slots_ls = (const float*)d_in[3];
  const float* Wq   = (const float*)d_in[4];
  const float* Wk   = (const float*)d_in[5];
  const float* Wv   = (const float*)d_in[6];
  const float* W_ih = (const float*)d_in[7];
  const float* W_hh = (const float*)d_in[8];
  const float* b_ih = (const float*)d_in[9];
  const float* b_hh = (const float*)d_in[10];
  const float* W1   = (const float*)d_in[11];
  const float* b1   = (const float*)d_in[12];
  const float* W2   = (const float*)d_in[13];
  const float* b2   = (const float*)d_in[14];
  const float* ln_in_g = (const float*)d_in[15];
  const float* ln_in_b = (const float*)d_in[16];
  const float* ln_s_g  = (const float*)d_in[17];
  const float* ln_s_b  = (const float*)d_in[18];
  const float* ln_ff_g = (const float*)d_in[19];
  const float* ln_ff_b = (const float*)d_in[20];
  float* out = (float*)d_out;

  char* w = (char*)d_ws;
  // region0: xbuf (ln_bf16 -> gemm) overlays gUp/gdp (attn -> update)
  u16* xbuf = (u16*)w;
  float* gUp = (float*)w;
  float* gdp = (float*)(w + (size_t)CH * 64 * 8 * 256 * 4);
  w += (size_t)GM * 256 * 2;                                  // 128 MB
  u16* kbuf = (u16*)w;     w += (size_t)GM * 256 * 2;         // 128 MB
  u16* vtbuf = (u16*)w;    w += (size_t)GM * 256 * 2;         // 128 MB
  u16* wkv = (u16*)w;      w += (size_t)512 * 256 * 2;        // 256 KB
  u16* Wcat = (u16*)w;     w += (size_t)1024 * 512 * 2;       // 1 MB
  u16* W1b = (u16*)w;      w += (size_t)512 * 256 * 2;        // 256 KB
  u16* W2b = (u16*)w;      w += (size_t)256 * 512 * 2;        // 256 KB
  u16* Wqb = (u16*)w;      w += (size_t)256 * 256 * 2;        // 128 KB
  float* slots = (float*)w; w += (size_t)131072 * 4;
  float* gq = (float*)w;    w += (size_t)131072 * 4;

  init_slots_kernel<<<512, 256, 0, stream>>>(noise, slots_mu, slots_ls, slots);
  wprep_kernel<<<3840, 256, 0, stream>>>(Wk, Wv, W_ih, W_hh, W1, W2, Wq,
                                         wkv, Wcat, W1b, W2b, Wqb);
  ln_bf16_kernel<<<GM / 4, 256, 0, stream>>>(inputs, ln_in_g, ln_in_b, xbuf);
  gemm_kv<<<dim3(GM / 128, 2), 512, 0, stream>>>(xbuf, wkv, kbuf, vtbuf);

  qproj_kernel<<<64, 256, 0, stream>>>(slots, Wq, ln_s_g, ln_s_b, gq);
  for (int it = 0; it < 3; ++it) {
    attn_kernel<<<dim3(CH, 64), 256, 0, stream>>>(kbuf, vtbuf, gq, gUp, gdp);
    update_kernel<<<64, 256, 0, stream>>>(gUp, gdp, slots, Wcat, b_ih, b_hh,
                                          W1b, b1, W2b, b2, ln_ff_g, ln_ff_b,
                                          Wqb, ln_s_g, ln_s_b, gq, out, it == 2);
  }
}

// Round 7
// 744.562 us; speedup vs baseline: 1.2392x; 1.0032x over previous
//
#include <hip/hip_runtime.h>

typedef unsigned short u16;
typedef unsigned int u32;
typedef __attribute__((ext_vector_type(4))) float f32x4;
typedef __attribute__((ext_vector_type(8))) short s16x8;

#define GM 262144   // B*N rows
#define GB 64
#define GN 4096
#define GC 256
#define GD 256
#define GS 8
#define GH 512
#define NPART 16    // U-partials per batch (one per attn block)

#define GLDS16(G, L) __builtin_amdgcn_global_load_lds( \
    (const __attribute__((address_space(1))) void*)(G), \
    (__attribute__((address_space(3))) void*)(L), 16, 0, 0)

__device__ __forceinline__ float bf2f(u16 u) {
  union { unsigned int i; float f; } c; c.i = ((unsigned int)u) << 16; return c.f;
}
__device__ __forceinline__ u16 f2bf(float f) {
  union { float f; unsigned int i; } c; c.f = f;
  unsigned int x = c.i;
  unsigned int r = x + 0x7FFFu + ((x >> 16) & 1u);
  return (u16)(r >> 16);
}
__device__ __forceinline__ float dot4(f32x4 a, f32x4 b) {
  return a.x*b.x + a.y*b.y + a.z*b.z + a.w*b.w;
}

// ---------------- slots init ----------------
__global__ void init_slots_kernel(const float* __restrict__ noise, const float* __restrict__ smu,
                                  const float* __restrict__ sls, float* __restrict__ slots)
{
  int i = blockIdx.x * 256 + threadIdx.x;
  int d = i & 255;
  slots[i] = smu[d] + expf(sls[d]) * noise[i];
}

// ---------------- weight prep: wkv, Wcat, W1b, W2b, Wqb (bf16) ----------------
// Wcat rows: [0,512) = [Wih_r,z | Whh_r,z]; [512,768) = [Wih_n | 0]; [768,1024) = [0 | Whh_n]
__global__ void wprep_kernel(const float* __restrict__ Wk, const float* __restrict__ Wv,
                             const float* __restrict__ Wih, const float* __restrict__ Whh,
                             const float* __restrict__ W1, const float* __restrict__ W2,
                             const float* __restrict__ Wq,
                             u16* __restrict__ wkv, u16* __restrict__ Wcat,
                             u16* __restrict__ W1b, u16* __restrict__ W2b,
                             u16* __restrict__ Wqb)
{
  int i = blockIdx.x * 256 + threadIdx.x;       // 983040 total
  if (i < 131072) {
    wkv[i] = f2bf(i < 65536 ? Wk[i] : Wv[i - 65536]);
  } else if (i < 655360) {
    int j2 = i - 131072;
    int r = j2 >> 9, k = j2 & 511;
    float v;
    if (r < 512)      v = (k < 256) ? Wih[r * 256 + k] : Whh[r * 256 + (k - 256)];
    else if (r < 768) v = (k < 256) ? Wih[r * 256 + k] : 0.f;
    else              v = (k < 256) ? 0.f : Whh[(r - 256) * 256 + (k - 256)];
    Wcat[j2] = f2bf(v);
  } else if (i < 786432) {
    W1b[i - 655360] = f2bf(W1[i - 655360]);
  } else if (i < 917504) {
    W2b[i - 786432] = f2bf(W2[i - 786432]);
  } else {
    Wqb[i - 917504] = f2bf(Wq[i - 917504]);
  }
}

// ---------------- LN(inputs) -> bf16 xbuf ----------------
__global__ __launch_bounds__(256) void ln_bf16_kernel(
    const float* __restrict__ x, const float* __restrict__ g, const float* __restrict__ be,
    u16* __restrict__ xbuf)
{
  int row = blockIdx.x * 4 + (threadIdx.x >> 6);
  int lane = threadIdx.x & 63;
  f32x4 v = *(const f32x4*)&x[(size_t)row * 256 + lane * 4];
  float s = v.x + v.y + v.z + v.w;
  float sq = v.x*v.x + v.y*v.y + v.z*v.z + v.w*v.w;
  #pragma unroll
  for (int m = 1; m < 64; m <<= 1) { s += __shfl_xor(s, m, 64); sq += __shfl_xor(sq, m, 64); }
  float mu = s * (1.f / 256.f);
  float var = sq * (1.f / 256.f) - mu * mu;
  float rstd = rsqrtf(var + 1e-3f);
  f32x4 gv = *(const f32x4*)&g[lane * 4];
  f32x4 bv = *(const f32x4*)&be[lane * 4];
  uint2 pk;
  pk.x = (u32)f2bf((v.x - mu) * rstd * gv.x + bv.x)
       | ((u32)f2bf((v.y - mu) * rstd * gv.y + bv.y) << 16);
  pk.y = (u32)f2bf((v.z - mu) * rstd * gv.z + bv.z)
       | ((u32)f2bf((v.w - mu) * rstd * gv.w + bv.w) << 16);
  *(uint2*)&xbuf[(size_t)row * 256 + lane * 4] = pk;
}

// ---------------- K/V projection GEMM: 128x256 tile, 8 waves, BK=64, swizzled GLDS16 ----------
// grid (2048, 2): cb=0 -> K (kbuf row-major), cb=1 -> V (vtbuf transposed tiles).
__global__ __launch_bounds__(512) void gemm_kv(
    const u16* __restrict__ xbuf, const u16* __restrict__ wkv,
    u16* __restrict__ kbuf, u16* __restrict__ vtbuf)
{
  __shared__ __align__(16) u16 As[128 * 64];   // 16 KB
  __shared__ __align__(16) u16 Bs[256 * 64];   // 32 KB
  const int t = threadIdx.x;
  const int brow = blockIdx.x * 128;
  const int cb = blockIdx.y;
  const int lane = t & 63, w = t >> 6;
  const int wr = w >> 2, wc = w & 3;           // wave grid 2 x 4 (64x64 each)
  const int fr = lane & 15, fq = lane >> 4;
  const int sx = fr & 7;

  const u16* aTile = xbuf + (size_t)brow * 256;
  const u16* bTile = wkv + (size_t)(cb << 8) * 256;

  f32x4 acc[4][4];
  #pragma unroll
  for (int i = 0; i < 4; ++i)
    #pragma unroll
    for (int j = 0; j < 4; ++j) { f32x4 z = {0.f,0.f,0.f,0.f}; acc[i][j] = z; }

  for (int kk = 0; kk < 256; kk += 64) {
    __syncthreads();
    #pragma unroll
    for (int c = 0; c < 2; ++c) {
      int q = c * 512 + t;
      int row = q >> 3, cc = q & 7;
      GLDS16(aTile + (size_t)row * 256 + kk + ((cc ^ (row & 7)) * 8), &As[q * 8]);
    }
    #pragma unroll
    for (int c = 0; c < 4; ++c) {
      int q = c * 512 + t;
      int row = q >> 3, cc = q & 7;
      GLDS16(bTile + (size_t)row * 256 + kk + ((cc ^ (row & 7)) * 8), &Bs[q * 8]);
    }
    asm volatile("s_waitcnt vmcnt(0)");
    __syncthreads();
    #pragma unroll
    for (int ks2 = 0; ks2 < 2; ++ks2) {
      s16x8 af[4], bf[4];
      #pragma unroll
      for (int i = 0; i < 4; ++i)
        af[i] = *(const s16x8*)&As[(wr * 64 + i * 16 + fr) * 64 + (((ks2 * 4 + fq) ^ sx) * 8)];
      #pragma unroll
      for (int j = 0; j < 4; ++j)
        bf[j] = *(const s16x8*)&Bs[(wc * 64 + j * 16 + fr) * 64 + (((ks2 * 4 + fq) ^ sx) * 8)];
      #pragma unroll
      for (int i = 0; i < 4; ++i)
        #pragma unroll
        for (int j = 0; j < 4; ++j)
          acc[i][j] = __builtin_amdgcn_mfma_f32_16x16x32_bf16(af[i], bf[j], acc[i][j], 0, 0, 0);
    }
  }

  if (cb == 0) {
    #pragma unroll
    for (int i = 0; i < 4; ++i)
      #pragma unroll
      for (int j = 0; j < 4; ++j)
        #pragma unroll
        for (int r = 0; r < 4; ++r)
          kbuf[(size_t)(brow + wr * 64 + i * 16 + fq * 4 + r) * 256 + wc * 64 + j * 16 + fr]
              = f2bf(acc[i][j][r]);
  } else {
    size_t base = (size_t)((brow >> 6) + wr) * 16384;
    #pragma unroll
    for (int i = 0; i < 4; ++i)
      #pragma unroll
      for (int j = 0; j < 4; ++j)
        #pragma unroll
        for (int r = 0; r < 4; ++r)
          vtbuf[base + (size_t)(wc * 64 + j * 16 + fr) * 64 + i * 16 + fq * 4 + r]
              = f2bf(acc[i][j][r]);
  }
}

// ---------------- slot LN + q projection (iter 0 only) ----------------
__global__ __launch_bounds__(256) void qproj_kernel(const float* __restrict__ slots, const float* __restrict__ Wq,
    const float* __restrict__ g, const float* __restrict__ be, float* __restrict__ gq)
{
  __shared__ __align__(16) float sl[8][256];
  int b = blockIdx.x, t = threadIdx.x;
  int lane = t & 63, w = t >> 6;
  #pragma unroll
  for (int s2 = 0; s2 < 2; ++s2) {
    int s = w * 2 + s2;
    f32x4 v = *(const f32x4*)&slots[(size_t)(b * 8 + s) * 256 + lane * 4];
    float s1 = v.x + v.y + v.z + v.w;
    float q1 = v.x*v.x + v.y*v.y + v.z*v.z + v.w*v.w;
    #pragma unroll
    for (int m = 1; m < 64; m <<= 1) { s1 += __shfl_xor(s1, m, 64); q1 += __shfl_xor(q1, m, 64); }
    float mu = s1 * (1.f / 256.f);
    float var = q1 * (1.f / 256.f) - mu * mu;
    float rstd = rsqrtf(var + 1e-3f);
    f32x4 gv = *(const f32x4*)&g[lane * 4];
    f32x4 bv = *(const f32x4*)&be[lane * 4];
    f32x4 o;
    o.x = (v.x - mu) * rstd * gv.x + bv.x;
    o.y = (v.y - mu) * rstd * gv.y + bv.y;
    o.z = (v.z - mu) * rstd * gv.z + bv.z;
    o.w = (v.w - mu) * rstd * gv.w + bv.w;
    *(f32x4*)&sl[s][lane * 4] = o;
  }
  __syncthreads();
  float a[8];
  #pragma unroll
  for (int s = 0; s < 8; ++s) a[s] = 0.f;
  const f32x4* wr = (const f32x4*)&Wq[(size_t)t * 256];
  for (int k = 0; k < 64; ++k) {
    f32x4 w4 = wr[k];
    #pragma unroll
    for (int s = 0; s < 8; ++s) a[s] += dot4(w4, *(const f32x4*)&sl[s][k * 4]);
  }
  #pragma unroll
  for (int s = 0; s < 8; ++s) gq[(size_t)(b * 8 + s) * 256 + t] = a[s] * 0.0625f;
}

// ---------------- barrier-free per-wave MFMA attention ----------------
// grid (16, 64), block 256 = 4 waves. Wave w owns n-tile nt = blockIdx.x*4 + w:
// 64 n-rows x all 256 d. K/V fragments global->reg direct; P transposed via
// per-wave LDS scratch (same-wave lgkm ordering, no barrier). One epilogue
// __syncthreads for the 4-wave U reduction -> one partial per block.
__global__ __launch_bounds__(256) void attn_kernel(
    const u16* __restrict__ kbuf, const u16* __restrict__ vtbuf,
    const float* __restrict__ gq, float* __restrict__ gUp, float* __restrict__ gdp)
{
  __shared__ __align__(16) u16 Pb[4][16 * 72];     // per-wave P scratch (bf16)
  __shared__ __align__(16) float Ured[4][2048];    // per-wave U for epilogue reduce
  __shared__ float denL[4][8];
  const int b = blockIdx.y, chunk = blockIdx.x;
  const int t = threadIdx.x;
  const int lane = t & 63, w = t >> 6;
  const int fr = lane & 15, fq = lane >> 4;
  const bool valid = fr < 8;
  const int nt = chunk * 4 + w;

  // --- q fragments (slot = fr, k-slice = ks*32 + fq*8) ---
  s16x8 qf[8];
  if (valid) {
    const float* qr = gq + (size_t)b * 2048 + fr * 256;
    #pragma unroll
    for (int ks = 0; ks < 8; ++ks) {
      f32x4 a = *(const f32x4*)&qr[ks * 32 + fq * 8];
      f32x4 c = *(const f32x4*)&qr[ks * 32 + fq * 8 + 4];
      s16x8 q8;
      q8[0] = (short)f2bf(a.x); q8[1] = (short)f2bf(a.y);
      q8[2] = (short)f2bf(a.z); q8[3] = (short)f2bf(a.w);
      q8[4] = (short)f2bf(c.x); q8[5] = (short)f2bf(c.y);
      q8[6] = (short)f2bf(c.z); q8[7] = (short)f2bf(c.w);
      qf[ks] = q8;
    }
  } else {
    #pragma unroll
    for (int ks = 0; ks < 8; ++ks) { s16x8 z = {0,0,0,0,0,0,0,0}; qf[ks] = z; }
  }

  const u16* kg = kbuf + ((size_t)b * 4096 + (size_t)nt * 64) * 256;
  const u16* vg = vtbuf + (size_t)(b * 64 + nt) * 16384;

  // --- dots: D[n][s], n-groups g of 16 rows ---
  f32x4 dacc[4];
  #pragma unroll
  for (int g = 0; g < 4; ++g) { f32x4 z = {0.f,0.f,0.f,0.f}; dacc[g] = z; }
  #pragma unroll
  for (int g = 0; g < 4; ++g) {
    #pragma unroll
    for (int ks = 0; ks < 8; ++ks) {
      s16x8 a = *(const s16x8*)&kg[(size_t)(g * 16 + fr) * 256 + ks * 32 + fq * 8];
      dacc[g] = __builtin_amdgcn_mfma_f32_16x16x32_bf16(a, qf[ks], dacc[g], 0, 0, 0);
    }
  }

  // --- softmax over slots (lane bits 0..2) + P write to per-wave LDS ---
  u32* pb32 = (u32*)&Pb[w][0];
  float denom_loc = 0.f;
  #pragma unroll
  for (int g = 0; g < 4; ++g) {
    float pw[4];
    #pragma unroll
    for (int r = 0; r < 4; ++r) {
      float d = dacc[g][r];
      float m = d;
      #pragma unroll
      for (int msk = 1; msk < 8; msk <<= 1) m = fmaxf(m, __shfl_xor(m, msk, 64));
      float e = expf(d - m);
      float sm = e;
      #pragma unroll
      for (int msk = 1; msk < 8; msk <<= 1) sm += __shfl_xor(sm, msk, 64);
      pw[r] = valid ? (e / sm + 1e-8f) : 0.f;
    }
    denom_loc += pw[0] + pw[1] + pw[2] + pw[3];
    pb32[fr * 36 + g * 8 + fq * 2]     = (u32)f2bf(pw[0]) | ((u32)f2bf(pw[1]) << 16);
    pb32[fr * 36 + g * 8 + fq * 2 + 1] = (u32)f2bf(pw[2]) | ((u32)f2bf(pw[3]) << 16);
  }

  // --- PV: U[s][d] += P[s][n] V[n][d]; V frags direct from vt tiles ---
  f32x4 uacc[16];
  #pragma unroll
  for (int ct = 0; ct < 16; ++ct) { f32x4 z = {0.f,0.f,0.f,0.f}; uacc[ct] = z; }
  #pragma unroll
  for (int c = 0; c < 2; ++c) {
    s16x8 pa = *(const s16x8*)&Pb[w][fr * 72 + c * 32 + fq * 8];
    #pragma unroll
    for (int ct = 0; ct < 16; ++ct) {
      s16x8 vb = *(const s16x8*)&vg[(size_t)(ct * 16 + fr) * 64 + c * 32 + fq * 8];
      uacc[ct] = __builtin_amdgcn_mfma_f32_16x16x32_bf16(pa, vb, uacc[ct], 0, 0, 0);
    }
  }

  // --- epilogue: block-reduce 4 waves -> one partial per block ---
  float dl = denom_loc;
  dl += __shfl_xor(dl, 16, 64);
  dl += __shfl_xor(dl, 32, 64);
  if (lane < 8) denL[w][lane] = dl;
  if (fq < 2) {
    #pragma unroll
    for (int ct = 0; ct < 16; ++ct)
      #pragma unroll
      for (int r = 0; r < 4; ++r)
        Ured[w][(fq * 4 + r) * 256 + ct * 16 + fr] = uacc[ct][r];
  }
  __syncthreads();
  {
    size_t obase = (size_t)(b * NPART + chunk) * 2048;
    #pragma unroll
    for (int i = 0; i < 8; ++i) {
      int idx = i * 256 + t;
      gUp[obase + idx] = Ured[0][idx] + Ured[1][idx] + Ured[2][idx] + Ured[3][idx];
    }
    if (t < 8) gdp[(b * NPART + chunk) * 8 + t] = denL[0][t] + denL[1][t] + denL[2][t] + denL[3][t];
  }
}

// ---------------- update: GRU + LN + MLP (+ fused next-iter qproj), MFMA M=16 GEMMs ----------
__global__ __launch_bounds__(256) void update_kernel(
    const float* __restrict__ gUp, const float* __restrict__ gdp,
    float* __restrict__ slots,
    const u16* __restrict__ Wcat, const float* __restrict__ b_ih, const float* __restrict__ b_hh,
    const u16* __restrict__ W1b, const float* __restrict__ b1,
    const u16* __restrict__ W2b, const float* __restrict__ b2,
    const float* __restrict__ lng, const float* __restrict__ lnb,
    const u16* __restrict__ Wqb, const float* __restrict__ lnsg, const float* __restrict__ lnsb,
    float* __restrict__ gq, float* __restrict__ out, int last)
{
  __shared__ __align__(16) u16 bufA[16 * 520];
  __shared__ __align__(16) u16 bufP[16 * 264];
  __shared__ float g[1024 * 10];
  __shared__ float nl[8 * 256];
  __shared__ float sp[8 * 256];
  __shared__ float scr[16];
  const int b = blockIdx.x;
  const int t = threadIdx.x;
  const int lane = t & 63, w = t >> 6;
  const int fr = lane & 15, fq = lane >> 4;

  // ---- phase 0 ----
  #pragma unroll
  for (int s = 0; s < 8; ++s) {
    float den = 0.f, ua = 0.f;
    #pragma unroll 4
    for (int c = 0; c < NPART; ++c) {
      den += gdp[(b * NPART + c) * 8 + s];
      ua  += gUp[(size_t)(b * NPART + c) * 2048 + s * 256 + t];
    }
    float u = ua / den;
    float spv = slots[(b * 8 + s) * 256 + t];
    bufA[s * 520 + t] = f2bf(u);
    bufA[s * 520 + 256 + t] = f2bf(spv);
    sp[s * 256 + t] = spv;
  }
  for (int i = t; i < 8 * 520; i += 256) bufA[8 * 520 + i] = 0;
  for (int i = t; i < 8 * 264; i += 256) bufP[8 * 264 + i] = 0;
  __syncthreads();

  // ---- phase 1: gates GEMM M=16 N=1024 K=512 ----
  {
    s16x8 afr[16];
    #pragma unroll
    for (int ks = 0; ks < 16; ++ks)
      afr[ks] = *(const s16x8*)&bufA[fr * 520 + ks * 32 + fq * 8];
    for (int nf = 0; nf < 16; ++nf) {
      int n0 = w * 256 + nf * 16;
      f32x4 acc = {0.f, 0.f, 0.f, 0.f};
      #pragma unroll
      for (int ks = 0; ks < 16; ++ks) {
        s16x8 bb = *(const s16x8*)&Wcat[(size_t)(n0 + fr) * 512 + ks * 32 + fq * 8];
        acc = __builtin_amdgcn_mfma_f32_16x16x32_bf16(afr[ks], bb, acc, 0, 0, 0);
      }
      if (fq < 2) {
        int j = n0 + fr;
        #pragma unroll
        for (int r = 0; r < 4; ++r) g[j * 10 + fq * 4 + r] = acc[r];
      }
    }
  }
  __syncthreads();

  // ---- phase 2: GRU elementwise ----
  {
    float bi0 = b_ih[t],       bh0 = b_hh[t];
    float bi1 = b_ih[256 + t], bh1 = b_hh[256 + t];
    float bi2 = b_ih[512 + t], bh2 = b_hh[512 + t];
    #pragma unroll
    for (int s = 0; s < 8; ++s) {
      float rr = 1.f / (1.f + expf(-(g[t * 10 + s] + bi0 + bh0)));
      float z  = 1.f / (1.f + expf(-(g[(256 + t) * 10 + s] + bi1 + bh1)));
      float xn = g[(512 + t) * 10 + s] + bi2;
      float hn = g[(768 + t) * 10 + s] + bh2;
      float nn = tanhf(xn + rr * hn);
      nl[s * 256 + t] = (1.f - z) * nn + z * sp[s * 256 + t];
    }
  }
  __syncthreads();

  // ---- LN_ff ----
  {
    int ln_ = t & 63;
    #pragma unroll
    for (int j = 0; j < 2; ++j) {
      int sl = w * 2 + j;
      f32x4 v = *(const f32x4*)&nl[sl * 256 + ln_ * 4];
      float s1 = v.x + v.y + v.z + v.w;
      float s2 = v.x*v.x + v.y*v.y + v.z*v.z + v.w*v.w;
      #pragma unroll
      for (int m = 1; m < 64; m <<= 1) { s1 += __shfl_xor(s1, m, 64); s2 += __shfl_xor(s2, m, 64); }
      if (ln_ == 0) {
        float mu = s1 * (1.f / 256.f);
        float var = s2 * (1.f / 256.f) - mu * mu;
        scr[sl * 2] = mu;
        scr[sl * 2 + 1] = rsqrtf(var + 1e-3f);
      }
    }
  }
  __syncthreads();
  {
    float lg = lng[t], lb = lnb[t];
    #pragma unroll
    for (int s = 0; s < 8; ++s)
      bufP[s * 264 + t] = f2bf((nl[s * 256 + t] - scr[s * 2]) * scr[s * 2 + 1] * lg + lb);
  }
  __syncthreads();

  // ---- phase 3: MLP1 M=16 N=512 K=256, relu ----
  {
    s16x8 pa[8];
    #pragma unroll
    for (int ks = 0; ks < 8; ++ks)
      pa[ks] = *(const s16x8*)&bufP[fr * 264 + ks * 32 + fq * 8];
    for (int nf = 0; nf < 8; ++nf) {
      int n0 = w * 128 + nf * 16;
      f32x4 acc = {0.f, 0.f, 0.f, 0.f};
      #pragma unroll
      for (int ks = 0; ks < 8; ++ks) {
        s16x8 bb = *(const s16x8*)&W1b[(size_t)(n0 + fr) * 256 + ks * 32 + fq * 8];
        acc = __builtin_amdgcn_mfma_f32_16x16x32_bf16(pa[ks], bb, acc, 0, 0, 0);
      }
      if (fq < 2) {
        float bb1 = b1[n0 + fr];
        #pragma unroll
        for (int r = 0; r < 4; ++r)
          bufA[(fq * 4 + r) * 520 + n0 + fr] = f2bf(fmaxf(acc[r] + bb1, 0.f));
      }
    }
  }
  __syncthreads();

  // ---- phase 4: MLP2 M=16 N=256 K=512, +residual; new slots -> sp ----
  {
    s16x8 ha[16];
    #pragma unroll
    for (int ks = 0; ks < 16; ++ks)
      ha[ks] = *(const s16x8*)&bufA[fr * 520 + ks * 32 + fq * 8];
    for (int nf = 0; nf < 4; ++nf) {
      int n0 = w * 64 + nf * 16;
      f32x4 acc = {0.f, 0.f, 0.f, 0.f};
      #pragma unroll
      for (int ks = 0; ks < 16; ++ks) {
        s16x8 bb = *(const s16x8*)&W2b[(size_t)(n0 + fr) * 512 + ks * 32 + fq * 8];
        acc = __builtin_amdgcn_mfma_f32_16x16x32_bf16(ha[ks], bb, acc, 0, 0, 0);
      }
      if (fq < 2) {
        int d = n0 + fr;
        float bb2 = b2[d];
        #pragma unroll
        for (int r = 0; r < 4; ++r) {
          int sl = fq * 4 + r;
          float val = acc[r] + nl[sl * 256 + d] + bb2;
          slots[(b * 8 + sl) * 256 + d] = val;
          sp[sl * 256 + d] = val;
          if (last) out[(b * 8 + sl) * 256 + d] = val;
        }
      }
    }
  }
  if (last) return;
  __syncthreads();

  // ---- fused next-iter qproj: LN_s(new slots) @ Wq^T * SCALE -> gq ----
  {
    int ln_ = t & 63;
    #pragma unroll
    for (int j = 0; j < 2; ++j) {
      int sl = w * 2 + j;
      f32x4 v = *(const f32x4*)&sp[sl * 256 + ln_ * 4];
      float s1 = v.x + v.y + v.z + v.w;
      float s2 = v.x*v.x + v.y*v.y + v.z*v.z + v.w*v.w;
      #pragma unroll
      for (int m = 1; m < 64; m <<= 1) { s1 += __shfl_xor(s1, m, 64); s2 += __shfl_xor(s2, m, 64); }
      if (ln_ == 0) {
        float mu = s1 * (1.f / 256.f);
        float var = s2 * (1.f / 256.f) - mu * mu;
        scr[sl * 2] = mu;
        scr[sl * 2 + 1] = rsqrtf(var + 1e-3f);
      }
    }
  }
  __syncthreads();
  {
    float lg = lnsg[t], lb = lnsb[t];
    #pragma unroll
    for (int s = 0; s < 8; ++s)
      bufP[s * 264 + t] = f2bf((sp[s * 256 + t] - scr[s * 2]) * scr[s * 2 + 1] * lg + lb);
  }
  __syncthreads();
  {
    s16x8 pa[8];
    #pragma unroll
    for (int ks = 0; ks < 8; ++ks)
      pa[ks] = *(const s16x8*)&bufP[fr * 264 + ks * 32 + fq * 8];
    for (int nf = 0; nf < 4; ++nf) {
      int n0 = w * 64 + nf * 16;
      f32x4 acc = {0.f, 0.f, 0.f, 0.f};
      #pragma unroll
      for (int ks = 0; ks < 8; ++ks) {
        s16x8 bb = *(const s16x8*)&Wqb[(size_t)(n0 + fr) * 256 + ks * 32 + fq * 8];
        acc = __builtin_amdgcn_mfma_f32_16x16x32_bf16(pa[ks], bb, acc, 0, 0, 0);
      }
      if (fq < 2) {
        int e = n0 + fr;
        #pragma unroll
        for (int r = 0; r < 4; ++r)
          gq[(size_t)(b * 8 + fq * 4 + r) * 256 + e] = acc[r] * 0.0625f;
      }
    }
  }
}

extern "C" void kernel_launch(void* const* d_in, const int* in_sizes, int n_in,
                              void* d_out, int out_size, void* d_ws, size_t ws_size,
                              hipStream_t stream) {
  const float* inputs   = (const float*)d_in[0];
  const float* noise    = (const float*)d_in[1];
  const float* slots_mu = (const float*)d_in[2];
  const float* slots_ls = (const float*)d_in[3];
  const float* Wq   = (const float*)d_in[4];
  const float* Wk   = (const float*)d_in[5];
  const float* Wv   = (const float*)d_in[6];
  const float* W_ih = (const float*)d_in[7];
  const float* W_hh = (const float*)d_in[8];
  const float* b_ih = (const float*)d_in[9];
  const float* b_hh = (const float*)d_in[10];
  const float* W1   = (const float*)d_in[11];
  const float* b1   = (const float*)d_in[12];
  const float* W2   = (const float*)d_in[13];
  const float* b2   = (const float*)d_in[14];
  const float* ln_in_g = (const float*)d_in[15];
  const float* ln_in_b = (const float*)d_in[16];
  const float* ln_s_g  = (const float*)d_in[17];
  const float* ln_s_b  = (const float*)d_in[18];
  const float* ln_ff_g = (const float*)d_in[19];
  const float* ln_ff_b = (const float*)d_in[20];
  float* out = (float*)d_out;

  char* w = (char*)d_ws;
  // region0: xbuf (ln_bf16 -> gemm) overlays gUp/gdp (attn -> update)
  u16* xbuf = (u16*)w;
  float* gUp = (float*)w;
  float* gdp = (float*)(w + (size_t)GB * NPART * 2048 * 4);   // 8 MB offset
  w += (size_t)GM * 256 * 2;                                  // 128 MB
  u16* kbuf = (u16*)w;     w += (size_t)GM * 256 * 2;         // 128 MB
  u16* vtbuf = (u16*)w;    w += (size_t)GM * 256 * 2;         // 128 MB
  u16* wkv = (u16*)w;      w += (size_t)512 * 256 * 2;        // 256 KB
  u16* Wcat = (u16*)w;     w += (size_t)1024 * 512 * 2;       // 1 MB
  u16* W1b = (u16*)w;      w += (size_t)512 * 256 * 2;        // 256 KB
  u16* W2b = (u16*)w;      w += (size_t)256 * 512 * 2;        // 256 KB
  u16* Wqb = (u16*)w;      w += (size_t)256 * 256 * 2;        // 128 KB
  float* slots = (float*)w; w += (size_t)131072 * 4;
  float* gq = (float*)w;    w += (size_t)131072 * 4;

  init_slots_kernel<<<512, 256, 0, stream>>>(noise, slots_mu, slots_ls, slots);
  wprep_kernel<<<3840, 256, 0, stream>>>(Wk, Wv, W_ih, W_hh, W1, W2, Wq,
                                         wkv, Wcat, W1b, W2b, Wqb);
  ln_bf16_kernel<<<GM / 4, 256, 0, stream>>>(inputs, ln_in_g, ln_in_b, xbuf);
  gemm_kv<<<dim3(GM / 128, 2), 512, 0, stream>>>(xbuf, wkv, kbuf, vtbuf);

  qproj_kernel<<<64, 256, 0, stream>>>(slots, Wq, ln_s_g, ln_s_b, gq);
  for (int it = 0; it < 3; ++it) {
    attn_kernel<<<dim3(NPART, 64), 256, 0, stream>>>(kbuf, vtbuf, gq, gUp, gdp);
    update_kernel<<<64, 256, 0, stream>>>(gUp, gdp, slots, Wcat, b_ih, b_hh,
                                          W1b, b1, W2b, b2, ln_ff_g, ln_ff_b,
                                          Wqb, ln_s_g, ln_s_b, gq, out, it == 2);
  }
}

// Round 8
// 664.195 us; speedup vs baseline: 1.3892x; 1.1210x over previous
//
#include <hip/hip_runtime.h>

typedef unsigned short u16;
typedef unsigned int u32;
typedef __attribute__((ext_vector_type(4))) float f32x4;
typedef __attribute__((ext_vector_type(8))) short s16x8;

#define GM 262144   // B*N rows
#define GB 64
#define GN 4096
#define GC 256
#define GD 256
#define GS 8
#define GH 512
#define NPART 16    // PX-partials per batch (one per attn block)

#define GLDS16(G, L) __builtin_amdgcn_global_load_lds( \
    (const __attribute__((address_space(1))) void*)(G), \
    (__attribute__((address_space(3))) void*)(L), 16, 0, 0)

__device__ __forceinline__ float bf2f(u16 u) {
  union { unsigned int i; float f; } c; c.i = ((unsigned int)u) << 16; return c.f;
}
__device__ __forceinline__ u16 f2bf(float f) {
  union { float f; unsigned int i; } c; c.f = f;
  unsigned int x = c.i;
  unsigned int r = x + 0x7FFFu + ((x >> 16) & 1u);
  return (u16)(r >> 16);
}
__device__ __forceinline__ float dot4(f32x4 a, f32x4 b) {
  return a.x*b.x + a.y*b.y + a.z*b.z + a.w*b.w;
}

// ---------------- slots init ----------------
__global__ void init_slots_kernel(const float* __restrict__ noise, const float* __restrict__ smu,
                                  const float* __restrict__ sls, float* __restrict__ slots)
{
  int i = blockIdx.x * 256 + threadIdx.x;
  int d = i & 255;
  slots[i] = smu[d] + expf(sls[d]) * noise[i];
}

// ---------------- weight prep: wkv(Wv part used), Wcat, W1b, W2b (bf16) ----------------
// Wcat rows: [0,512) = [Wih_r,z | Whh_r,z]; [512,768) = [Wih_n | 0]; [768,1024) = [0 | Whh_n]
__global__ void wprep_kernel(const float* __restrict__ Wk, const float* __restrict__ Wv,
                             const float* __restrict__ Wih, const float* __restrict__ Whh,
                             const float* __restrict__ W1, const float* __restrict__ W2,
                             u16* __restrict__ wkv, u16* __restrict__ Wcat,
                             u16* __restrict__ W1b, u16* __restrict__ W2b)
{
  int i = blockIdx.x * 256 + threadIdx.x;       // 917504 total
  if (i < 131072) {
    wkv[i] = f2bf(i < 65536 ? Wk[i] : Wv[i - 65536]);
  } else if (i < 655360) {
    int j2 = i - 131072;
    int r = j2 >> 9, k = j2 & 511;
    float v;
    if (r < 512)      v = (k < 256) ? Wih[r * 256 + k] : Whh[r * 256 + (k - 256)];
    else if (r < 768) v = (k < 256) ? Wih[r * 256 + k] : 0.f;
    else              v = (k < 256) ? 0.f : Whh[(r - 256) * 256 + (k - 256)];
    Wcat[j2] = f2bf(v);
  } else if (i < 786432) {
    W1b[i - 655360] = f2bf(W1[i - 655360]);
  } else {
    W2b[i - 786432] = f2bf(W2[i - 786432]);
  }
}

// ---------------- WqkT = SCALE * Wk^T @ Wq  (fp32 + bf16) ----------------
// block c (256), thread e (256): WqkT[c][e] = SCALE * sum_d Wk[d][c] * Wq[d][e]
__global__ __launch_bounds__(256) void wqk_kernel(
    const float* __restrict__ Wk, const float* __restrict__ Wq,
    float* __restrict__ WqkT, u16* __restrict__ WqkTb)
{
  __shared__ float wkc[256];
  int c = blockIdx.x, t = threadIdx.x;
  wkc[t] = Wk[t * 256 + c];
  __syncthreads();
  float a0 = 0.f, a1 = 0.f, a2 = 0.f, a3 = 0.f;
  #pragma unroll 4
  for (int d = 0; d < 256; d += 4) {
    a0 += wkc[d]     * Wq[(d)     * 256 + t];
    a1 += wkc[d + 1] * Wq[(d + 1) * 256 + t];
    a2 += wkc[d + 2] * Wq[(d + 2) * 256 + t];
    a3 += wkc[d + 3] * Wq[(d + 3) * 256 + t];
  }
  float acc = (a0 + a1 + a2 + a3) * 0.0625f;   // SCALE folded
  WqkT[c * 256 + t] = acc;
  WqkTb[c * 256 + t] = f2bf(acc);
}

// ---------------- LN(inputs) -> bf16 xbuf ----------------
__global__ __launch_bounds__(256) void ln_bf16_kernel(
    const float* __restrict__ x, const float* __restrict__ g, const float* __restrict__ be,
    u16* __restrict__ xbuf)
{
  int row = blockIdx.x * 4 + (threadIdx.x >> 6);
  int lane = threadIdx.x & 63;
  f32x4 v = *(const f32x4*)&x[(size_t)row * 256 + lane * 4];
  float s = v.x + v.y + v.z + v.w;
  float sq = v.x*v.x + v.y*v.y + v.z*v.z + v.w*v.w;
  #pragma unroll
  for (int m = 1; m < 64; m <<= 1) { s += __shfl_xor(s, m, 64); sq += __shfl_xor(sq, m, 64); }
  float mu = s * (1.f / 256.f);
  float var = sq * (1.f / 256.f) - mu * mu;
  float rstd = rsqrtf(var + 1e-3f);
  f32x4 gv = *(const f32x4*)&g[lane * 4];
  f32x4 bv = *(const f32x4*)&be[lane * 4];
  uint2 pk;
  pk.x = (u32)f2bf((v.x - mu) * rstd * gv.x + bv.x)
       | ((u32)f2bf((v.y - mu) * rstd * gv.y + bv.y) << 16);
  pk.y = (u32)f2bf((v.z - mu) * rstd * gv.z + bv.z)
       | ((u32)f2bf((v.w - mu) * rstd * gv.w + bv.w) << 16);
  *(uint2*)&xbuf[(size_t)row * 256 + lane * 4] = pk;
}

// ---------------- transpose: xbuf tiles [64][256] -> xtbuf [tile][c 256][n 64] ----------------
// grid 4096, block 256. GLDS16 staging with source-chunk XOR swizzle (cg ^ row>>3) so the
// column-gather LDS reads hit 32 distinct banks (2 lanes/bank = free). Writes coalesced 16B.
__global__ __launch_bounds__(256) void xt_kernel(
    const u16* __restrict__ xbuf, u16* __restrict__ xtbuf)
{
  __shared__ __align__(16) u16 tl[64 * 256];
  const int t = threadIdx.x;
  const size_t tbase = (size_t)blockIdx.x * 16384;
  const u16* src = xbuf + tbase;

  #pragma unroll
  for (int p = 0; p < 8; ++p) {
    int q = p * 256 + t;
    int row = q >> 5, cg = q & 31;
    GLDS16(src + (size_t)row * 256 + ((cg ^ (row >> 3)) * 8), &tl[q * 8]);
  }
  asm volatile("s_waitcnt vmcnt(0)");
  __syncthreads();

  u16* dst = xtbuf + tbase;
  #pragma unroll
  for (int i = 0; i < 8; ++i) {
    int q = i * 256 + t;
    int c = q >> 3, ng = q & 7;
    int cs = ((c >> 3) ^ ng) * 8 + (c & 7);     // swizzled column offset (row>>3 == ng)
    u16 v0 = tl[(ng * 8 + 0) * 256 + cs];
    u16 v1 = tl[(ng * 8 + 1) * 256 + cs];
    u16 v2 = tl[(ng * 8 + 2) * 256 + cs];
    u16 v3 = tl[(ng * 8 + 3) * 256 + cs];
    u16 v4 = tl[(ng * 8 + 4) * 256 + cs];
    u16 v5 = tl[(ng * 8 + 5) * 256 + cs];
    u16 v6 = tl[(ng * 8 + 6) * 256 + cs];
    u16 v7 = tl[(ng * 8 + 7) * 256 + cs];
    uint4 pk;
    pk.x = (u32)v0 | ((u32)v1 << 16);
    pk.y = (u32)v2 | ((u32)v3 << 16);
    pk.z = (u32)v4 | ((u32)v5 << 16);
    pk.w = (u32)v6 | ((u32)v7 << 16);
    *(uint4*)&dst[(size_t)c * 64 + ng * 8] = pk;
  }
}

// ---------------- slot LN + q->input-space projection (iter 0 only) ----------------
__global__ __launch_bounds__(256) void qproj_kernel(const float* __restrict__ slots,
    const float* __restrict__ WqkT,
    const float* __restrict__ g, const float* __restrict__ be, float* __restrict__ gqk)
{
  __shared__ __align__(16) float sl[8][256];
  int b = blockIdx.x, t = threadIdx.x;
  int lane = t & 63, w = t >> 6;
  #pragma unroll
  for (int s2 = 0; s2 < 2; ++s2) {
    int s = w * 2 + s2;
    f32x4 v = *(const f32x4*)&slots[(size_t)(b * 8 + s) * 256 + lane * 4];
    float s1 = v.x + v.y + v.z + v.w;
    float q1 = v.x*v.x + v.y*v.y + v.z*v.z + v.w*v.w;
    #pragma unroll
    for (int m = 1; m < 64; m <<= 1) { s1 += __shfl_xor(s1, m, 64); q1 += __shfl_xor(q1, m, 64); }
    float mu = s1 * (1.f / 256.f);
    float var = q1 * (1.f / 256.f) - mu * mu;
    float rstd = rsqrtf(var + 1e-3f);
    f32x4 gv = *(const f32x4*)&g[lane * 4];
    f32x4 bv = *(const f32x4*)&be[lane * 4];
    f32x4 o;
    o.x = (v.x - mu) * rstd * gv.x + bv.x;
    o.y = (v.y - mu) * rstd * gv.y + bv.y;
    o.z = (v.z - mu) * rstd * gv.z + bv.z;
    o.w = (v.w - mu) * rstd * gv.w + bv.w;
    *(f32x4*)&sl[s][lane * 4] = o;
  }
  __syncthreads();
  float a[8];
  #pragma unroll
  for (int s = 0; s < 8; ++s) a[s] = 0.f;
  const f32x4* wr = (const f32x4*)&WqkT[(size_t)t * 256];
  for (int k = 0; k < 64; ++k) {
    f32x4 w4 = wr[k];
    #pragma unroll
    for (int s = 0; s < 8; ++s) a[s] += dot4(w4, *(const f32x4*)&sl[s][k * 4]);
  }
  #pragma unroll
  for (int s = 0; s < 8; ++s) gqk[(size_t)(b * 8 + s) * 256 + t] = a[s];   // SCALE already folded
}

// ---------------- barrier-free per-wave MFMA attention (PX = P @ xln) ----------------
// grid (16, 64), block 256 = 4 waves. Wave w owns n-tile nt = blockIdx.x*4 + w.
// Identical structure to before; K-operand = xbuf rows, "V"-operand = xt tiles.
__global__ __launch_bounds__(256) void attn_kernel(
    const u16* __restrict__ xb, const u16* __restrict__ xtb,
    const float* __restrict__ gqk, float* __restrict__ gUp, float* __restrict__ gdp)
{
  __shared__ __align__(16) u16 Pb[4][16 * 72];     // per-wave P scratch (bf16)
  __shared__ __align__(16) float Ured[4][2048];    // per-wave PX for epilogue reduce
  __shared__ float denL[4][8];
  const int b = blockIdx.y, chunk = blockIdx.x;
  const int t = threadIdx.x;
  const int lane = t & 63, w = t >> 6;
  const int fr = lane & 15, fq = lane >> 4;
  const bool valid = fr < 8;
  const int nt = chunk * 4 + w;

  // --- q fragments (slot = fr, k-slice = ks*32 + fq*8) ---
  s16x8 qf[8];
  if (valid) {
    const float* qr = gqk + (size_t)b * 2048 + fr * 256;
    #pragma unroll
    for (int ks = 0; ks < 8; ++ks) {
      f32x4 a = *(const f32x4*)&qr[ks * 32 + fq * 8];
      f32x4 c = *(const f32x4*)&qr[ks * 32 + fq * 8 + 4];
      s16x8 q8;
      q8[0] = (short)f2bf(a.x); q8[1] = (short)f2bf(a.y);
      q8[2] = (short)f2bf(a.z); q8[3] = (short)f2bf(a.w);
      q8[4] = (short)f2bf(c.x); q8[5] = (short)f2bf(c.y);
      q8[6] = (short)f2bf(c.z); q8[7] = (short)f2bf(c.w);
      qf[ks] = q8;
    }
  } else {
    #pragma unroll
    for (int ks = 0; ks < 8; ++ks) { s16x8 z = {0,0,0,0,0,0,0,0}; qf[ks] = z; }
  }

  const u16* kg = xb + ((size_t)b * 4096 + (size_t)nt * 64) * 256;
  const u16* vg = xtb + (size_t)(b * 64 + nt) * 16384;

  // --- dots: D[n][s] ---
  f32x4 dacc[4];
  #pragma unroll
  for (int g = 0; g < 4; ++g) { f32x4 z = {0.f,0.f,0.f,0.f}; dacc[g] = z; }
  #pragma unroll
  for (int g = 0; g < 4; ++g) {
    #pragma unroll
    for (int ks = 0; ks < 8; ++ks) {
      s16x8 a = *(const s16x8*)&kg[(size_t)(g * 16 + fr) * 256 + ks * 32 + fq * 8];
      dacc[g] = __builtin_amdgcn_mfma_f32_16x16x32_bf16(a, qf[ks], dacc[g], 0, 0, 0);
    }
  }

  // --- softmax over slots (lane bits 0..2) + P write to per-wave LDS ---
  u32* pb32 = (u32*)&Pb[w][0];
  float denom_loc = 0.f;
  #pragma unroll
  for (int g = 0; g < 4; ++g) {
    float pw[4];
    #pragma unroll
    for (int r = 0; r < 4; ++r) {
      float d = dacc[g][r];
      float m = d;
      #pragma unroll
      for (int msk = 1; msk < 8; msk <<= 1) m = fmaxf(m, __shfl_xor(m, msk, 64));
      float e = expf(d - m);
      float sm = e;
      #pragma unroll
      for (int msk = 1; msk < 8; msk <<= 1) sm += __shfl_xor(sm, msk, 64);
      pw[r] = valid ? (e / sm + 1e-8f) : 0.f;
    }
    denom_loc += pw[0] + pw[1] + pw[2] + pw[3];
    pb32[fr * 36 + g * 8 + fq * 2]     = (u32)f2bf(pw[0]) | ((u32)f2bf(pw[1]) << 16);
    pb32[fr * 36 + g * 8 + fq * 2 + 1] = (u32)f2bf(pw[2]) | ((u32)f2bf(pw[3]) << 16);
  }

  // --- PX: U[s][c] += P[s][n] xln[n][c] ---
  f32x4 uacc[16];
  #pragma unroll
  for (int ct = 0; ct < 16; ++ct) { f32x4 z = {0.f,0.f,0.f,0.f}; uacc[ct] = z; }
  #pragma unroll
  for (int c = 0; c < 2; ++c) {
    s16x8 pa = *(const s16x8*)&Pb[w][fr * 72 + c * 32 + fq * 8];
    #pragma unroll
    for (int ct = 0; ct < 16; ++ct) {
      s16x8 vb = *(const s16x8*)&vg[(size_t)(ct * 16 + fr) * 64 + c * 32 + fq * 8];
      uacc[ct] = __builtin_amdgcn_mfma_f32_16x16x32_bf16(pa, vb, uacc[ct], 0, 0, 0);
    }
  }

  // --- epilogue: block-reduce 4 waves -> one partial per block ---
  float dl = denom_loc;
  dl += __shfl_xor(dl, 16, 64);
  dl += __shfl_xor(dl, 32, 64);
  if (lane < 8) denL[w][lane] = dl;
  if (fq < 2) {
    #pragma unroll
    for (int ct = 0; ct < 16; ++ct)
      #pragma unroll
      for (int r = 0; r < 4; ++r)
        Ured[w][(fq * 4 + r) * 256 + ct * 16 + fr] = uacc[ct][r];
  }
  __syncthreads();
  {
    size_t obase = (size_t)(b * NPART + chunk) * 2048;
    #pragma unroll
    for (int i = 0; i < 8; ++i) {
      int idx = i * 256 + t;
      gUp[obase + idx] = Ured[0][idx] + Ured[1][idx] + Ured[2][idx] + Ured[3][idx];
    }
    if (t < 8) gdp[(b * NPART + chunk) * 8 + t] = denL[0][t] + denL[1][t] + denL[2][t] + denL[3][t];
  }
}

// ---------------- update: Wv-proj + GRU + LN + MLP (+ fused next-iter qproj) ----------------
__global__ __launch_bounds__(256) void update_kernel(
    const float* __restrict__ gUp, const float* __restrict__ gdp,
    float* __restrict__ slots,
    const u16* __restrict__ WvB,
    const u16* __restrict__ Wcat, const float* __restrict__ b_ih, const float* __restrict__ b_hh,
    const u16* __restrict__ W1b, const float* __restrict__ b1,
    const u16* __restrict__ W2b, const float* __restrict__ b2,
    const float* __restrict__ lng, const float* __restrict__ lnb,
    const u16* __restrict__ WqkTb, const float* __restrict__ lnsg, const float* __restrict__ lnsb,
    float* __restrict__ gqk, float* __restrict__ out, int last)
{
  __shared__ __align__(16) u16 bufA[16 * 520];
  __shared__ __align__(16) u16 bufP[16 * 264];
  __shared__ __align__(16) u16 bufU[16 * 264];
  __shared__ float g[1024 * 10];
  __shared__ float nl[8 * 256];
  __shared__ float sp[8 * 256];
  __shared__ float scr[16];
  const int b = blockIdx.x;
  const int t = threadIdx.x;
  const int lane = t & 63, w = t >> 6;
  const int fr = lane & 15, fq = lane >> 4;

  // ---- phase 0: PXn = sum(partials)/denom (bf16); prev slots ----
  #pragma unroll
  for (int s = 0; s < 8; ++s) {
    float den = 0.f, ua = 0.f;
    #pragma unroll 4
    for (int c = 0; c < NPART; ++c) {
      den += gdp[(b * NPART + c) * 8 + s];
      ua  += gUp[(size_t)(b * NPART + c) * 2048 + s * 256 + t];
    }
    bufU[s * 264 + t] = f2bf(ua / den);
    float spv = slots[(b * 8 + s) * 256 + t];
    bufA[s * 520 + 256 + t] = f2bf(spv);
    sp[s * 256 + t] = spv;
  }
  for (int i = t; i < 8 * 520; i += 256) bufA[8 * 520 + i] = 0;
  for (int i = t; i < 8 * 264; i += 256) { bufP[8 * 264 + i] = 0; bufU[8 * 264 + i] = 0; }
  __syncthreads();

  // ---- phase 0b: updates = PXn @ Wv^T  (M=16, N=256, K=256) -> bufA u-part ----
  {
    s16x8 pa[8];
    #pragma unroll
    for (int ks = 0; ks < 8; ++ks)
      pa[ks] = *(const s16x8*)&bufU[fr * 264 + ks * 32 + fq * 8];
    for (int nf = 0; nf < 4; ++nf) {
      int n0 = w * 64 + nf * 16;
      f32x4 acc = {0.f, 0.f, 0.f, 0.f};
      #pragma unroll
      for (int ks = 0; ks < 8; ++ks) {
        s16x8 bb = *(const s16x8*)&WvB[(size_t)(n0 + fr) * 256 + ks * 32 + fq * 8];
        acc = __builtin_amdgcn_mfma_f32_16x16x32_bf16(pa[ks], bb, acc, 0, 0, 0);
      }
      if (fq < 2) {
        int d = n0 + fr;
        #pragma unroll
        for (int r = 0; r < 4; ++r)
          bufA[(fq * 4 + r) * 520 + d] = f2bf(acc[r]);
      }
    }
  }
  __syncthreads();

  // ---- phase 1: gates GEMM M=16 N=1024 K=512 ----
  {
    s16x8 afr[16];
    #pragma unroll
    for (int ks = 0; ks < 16; ++ks)
      afr[ks] = *(const s16x8*)&bufA[fr * 520 + ks * 32 + fq * 8];
    for (int nf = 0; nf < 16; ++nf) {
      int n0 = w * 256 + nf * 16;
      f32x4 acc = {0.f, 0.f, 0.f, 0.f};
      #pragma unroll
      for (int ks = 0; ks < 16; ++ks) {
        s16x8 bb = *(const s16x8*)&Wcat[(size_t)(n0 + fr) * 512 + ks * 32 + fq * 8];
        acc = __builtin_amdgcn_mfma_f32_16x16x32_bf16(afr[ks], bb, acc, 0, 0, 0);
      }
      if (fq < 2) {
        int j = n0 + fr;
        #pragma unroll
        for (int r = 0; r < 4; ++r) g[j * 10 + fq * 4 + r] = acc[r];
      }
    }
  }
  __syncthreads();

  // ---- phase 2: GRU elementwise ----
  {
    float bi0 = b_ih[t],       bh0 = b_hh[t];
    float bi1 = b_ih[256 + t], bh1 = b_hh[256 + t];
    float bi2 = b_ih[512 + t], bh2 = b_hh[512 + t];
    #pragma unroll
    for (int s = 0; s < 8; ++s) {
      float rr = 1.f / (1.f + expf(-(g[t * 10 + s] + bi0 + bh0)));
      float z  = 1.f / (1.f + expf(-(g[(256 + t) * 10 + s] + bi1 + bh1)));
      float xn = g[(512 + t) * 10 + s] + bi2;
      float hn = g[(768 + t) * 10 + s] + bh2;
      float nn = tanhf(xn + rr * hn);
      nl[s * 256 + t] = (1.f - z) * nn + z * sp[s * 256 + t];
    }
  }
  __syncthreads();

  // ---- LN_ff ----
  {
    int ln_ = t & 63;
    #pragma unroll
    for (int j = 0; j < 2; ++j) {
      int sl = w * 2 + j;
      f32x4 v = *(const f32x4*)&nl[sl * 256 + ln_ * 4];
      float s1 = v.x + v.y + v.z + v.w;
      float s2 = v.x*v.x + v.y*v.y + v.z*v.z + v.w*v.w;
      #pragma unroll
      for (int m = 1; m < 64; m <<= 1) { s1 += __shfl_xor(s1, m, 64); s2 += __shfl_xor(s2, m, 64); }
      if (ln_ == 0) {
        float mu = s1 * (1.f / 256.f);
        float var = s2 * (1.f / 256.f) - mu * mu;
        scr[sl * 2] = mu;
        scr[sl * 2 + 1] = rsqrtf(var + 1e-3f);
      }
    }
  }
  __syncthreads();
  {
    float lg = lng[t], lb = lnb[t];
    #pragma unroll
    for (int s = 0; s < 8; ++s)
      bufP[s * 264 + t] = f2bf((nl[s * 256 + t] - scr[s * 2]) * scr[s * 2 + 1] * lg + lb);
  }
  __syncthreads();

  // ---- phase 3: MLP1 M=16 N=512 K=256, relu ----
  {
    s16x8 pa[8];
    #pragma unroll
    for (int ks = 0; ks < 8; ++ks)
      pa[ks] = *(const s16x8*)&bufP[fr * 264 + ks * 32 + fq * 8];
    for (int nf = 0; nf < 8; ++nf) {
      int n0 = w * 128 + nf * 16;
      f32x4 acc = {0.f, 0.f, 0.f, 0.f};
      #pragma unroll
      for (int ks = 0; ks < 8; ++ks) {
        s16x8 bb = *(const s16x8*)&W1b[(size_t)(n0 + fr) * 256 + ks * 32 + fq * 8];
        acc = __builtin_amdgcn_mfma_f32_16x16x32_bf16(pa[ks], bb, acc, 0, 0, 0);
      }
      if (fq < 2) {
        float bb1 = b1[n0 + fr];
        #pragma unroll
        for (int r = 0; r < 4; ++r)
          bufA[(fq * 4 + r) * 520 + n0 + fr] = f2bf(fmaxf(acc[r] + bb1, 0.f));
      }
    }
  }
  __syncthreads();

  // ---- phase 4: MLP2 M=16 N=256 K=512, +residual; new slots -> sp ----
  {
    s16x8 ha[16];
    #pragma unroll
    for (int ks = 0; ks < 16; ++ks)
      ha[ks] = *(const s16x8*)&bufA[fr * 520 + ks * 32 + fq * 8];
    for (int nf = 0; nf < 4; ++nf) {
      int n0 = w * 64 + nf * 16;
      f32x4 acc = {0.f, 0.f, 0.f, 0.f};
      #pragma unroll
      for (int ks = 0; ks < 16; ++ks) {
        s16x8 bb = *(const s16x8*)&W2b[(size_t)(n0 + fr) * 512 + ks * 32 + fq * 8];
        acc = __builtin_amdgcn_mfma_f32_16x16x32_bf16(ha[ks], bb, acc, 0, 0, 0);
      }
      if (fq < 2) {
        int d = n0 + fr;
        float bb2 = b2[d];
        #pragma unroll
        for (int r = 0; r < 4; ++r) {
          int sl = fq * 4 + r;
          float val = acc[r] + nl[sl * 256 + d] + bb2;
          slots[(b * 8 + sl) * 256 + d] = val;
          sp[sl * 256 + d] = val;
          if (last) out[(b * 8 + sl) * 256 + d] = val;
        }
      }
    }
  }
  if (last) return;
  __syncthreads();

  // ---- fused next-iter qproj: gqk = LN_s(new slots) @ WqkT (SCALE folded) ----
  {
    int ln_ = t & 63;
    #pragma unroll
    for (int j = 0; j < 2; ++j) {
      int sl = w * 2 + j;
      f32x4 v = *(const f32x4*)&sp[sl * 256 + ln_ * 4];
      float s1 = v.x + v.y + v.z + v.w;
      float s2 = v.x*v.x + v.y*v.y + v.z*v.z + v.w*v.w;
      #pragma unroll
      for (int m = 1; m < 64; m <<= 1) { s1 += __shfl_xor(s1, m, 64); s2 += __shfl_xor(s2, m, 64); }
      if (ln_ == 0) {
        float mu = s1 * (1.f / 256.f);
        float var = s2 * (1.f / 256.f) - mu * mu;
        scr[sl * 2] = mu;
        scr[sl * 2 + 1] = rsqrtf(var + 1e-3f);
      }
    }
  }
  __syncthreads();
  {
    float lg = lnsg[t], lb = lnsb[t];
    #pragma unroll
    for (int s = 0; s < 8; ++s)
      bufP[s * 264 + t] = f2bf((sp[s * 256 + t] - scr[s * 2]) * scr[s * 2 + 1] * lg + lb);
  }
  __syncthreads();
  {
    s16x8 pa[8];
    #pragma unroll
    for (int ks = 0; ks < 8; ++ks)
      pa[ks] = *(const s16x8*)&bufP[fr * 264 + ks * 32 + fq * 8];
    for (int nf = 0; nf < 4; ++nf) {
      int n0 = w * 64 + nf * 16;
      f32x4 acc = {0.f, 0.f, 0.f, 0.f};
      #pragma unroll
      for (int ks = 0; ks < 8; ++ks) {
        s16x8 bb = *(const s16x8*)&WqkTb[(size_t)(n0 + fr) * 256 + ks * 32 + fq * 8];
        acc = __builtin_amdgcn_mfma_f32_16x16x32_bf16(pa[ks], bb, acc, 0, 0, 0);
      }
      if (fq < 2) {
        int e = n0 + fr;
        #pragma unroll
        for (int r = 0; r < 4; ++r)
          gqk[(size_t)(b * 8 + fq * 4 + r) * 256 + e] = acc[r];
      }
    }
  }
}

extern "C" void kernel_launch(void* const* d_in, const int* in_sizes, int n_in,
                              void* d_out, int out_size, void* d_ws, size_t ws_size,
                              hipStream_t stream) {
  const float* inputs   = (const float*)d_in[0];
  const float* noise    = (const float*)d_in[1];
  const float* slots_mu = (const float*)d_in[2];
  const float* slots_ls = (const float*)d_in[3];
  const float* Wq   = (const float*)d_in[4];
  const float* Wk   = (const float*)d_in[5];
  const float* Wv   = (const float*)d_in[6];
  const float* W_ih = (const float*)d_in[7];
  const float* W_hh = (const float*)d_in[8];
  const float* b_ih = (const float*)d_in[9];
  const float* b_hh = (const float*)d_in[10];
  const float* W1   = (const float*)d_in[11];
  const float* b1   = (const float*)d_in[12];
  const float* W2   = (const float*)d_in[13];
  const float* b2   = (const float*)d_in[14];
  const float* ln_in_g = (const float*)d_in[15];
  const float* ln_in_b = (const float*)d_in[16];
  const float* ln_s_g  = (const float*)d_in[17];
  const float* ln_s_b  = (const float*)d_in[18];
  const float* ln_ff_g = (const float*)d_in[19];
  const float* ln_ff_b = (const float*)d_in[20];
  float* out = (float*)d_out;

  char* w = (char*)d_ws;
  u16* xbuf = (u16*)w;      w += (size_t)GM * 256 * 2;        // 128 MB (persistent: attn reads)
  float* gUp = (float*)w;                                     // scratch region (old kbuf)
  float* gdp = (float*)(w + (size_t)GB * NPART * 2048 * 4);
  w += (size_t)GM * 256 * 2;                                  // 128 MB
  u16* xtbuf = (u16*)w;     w += (size_t)GM * 256 * 2;        // 128 MB (transposed tiles)
  u16* wkv = (u16*)w;       w += (size_t)512 * 256 * 2;       // 256 KB (Wk|Wv bf16; Wv part used)
  u16* Wcat = (u16*)w;      w += (size_t)1024 * 512 * 2;      // 1 MB
  u16* W1b = (u16*)w;       w += (size_t)512 * 256 * 2;       // 256 KB
  u16* W2b = (u16*)w;       w += (size_t)256 * 512 * 2;       // 256 KB
  float* WqkT = (float*)w;  w += (size_t)256 * 256 * 4;       // 256 KB fp32
  u16* WqkTb = (u16*)w;     w += (size_t)256 * 256 * 2;       // 128 KB bf16
  float* slots = (float*)w; w += (size_t)131072 * 4;
  float* gqk = (float*)w;   w += (size_t)131072 * 4;

  u16* WvB = wkv + 65536;   // Wv bf16 [d][c]

  init_slots_kernel<<<512, 256, 0, stream>>>(noise, slots_mu, slots_ls, slots);
  wprep_kernel<<<3584, 256, 0, stream>>>(Wk, Wv, W_ih, W_hh, W1, W2, wkv, Wcat, W1b, W2b);
  wqk_kernel<<<256, 256, 0, stream>>>(Wk, Wq, WqkT, WqkTb);
  ln_bf16_kernel<<<GM / 4, 256, 0, stream>>>(inputs, ln_in_g, ln_in_b, xbuf);
  xt_kernel<<<GM / 64, 256, 0, stream>>>(xbuf, xtbuf);

  qproj_kernel<<<64, 256, 0, stream>>>(slots, WqkT, ln_s_g, ln_s_b, gqk);
  for (int it = 0; it < 3; ++it) {
    attn_kernel<<<dim3(NPART, 64), 256, 0, stream>>>(xbuf, xtbuf, gqk, gUp, gdp);
    update_kernel<<<64, 256, 0, stream>>>(gUp, gdp, slots, WvB, Wcat, b_ih, b_hh,
                                          W1b, b1, W2b, b2, ln_ff_g, ln_ff_b,
                                          WqkTb, ln_s_g, ln_s_b, gqk, out, it == 2);
  }
}